// Round 21
// baseline (656.496 us; speedup 1.0000x reference)
//
#include <hip/hip_runtime.h>
#include <math.h>

#define B_ROWS 1024
#define D_IN   2048
#define D_HID  4096
#define D_UP   4096
#define NH     8
#define HS     512
#define LN_EPS 1e-5f

typedef __attribute__((ext_vector_type(8))) short bf16x8_t;
typedef __attribute__((ext_vector_type(4))) float f32x4_t;
typedef __attribute__((ext_vector_type(4))) unsigned short us4_t;

__device__ __forceinline__ unsigned short f2bf(float f) {
    unsigned int u = __float_as_uint(f);
    u += 0x7fffu + ((u >> 16) & 1u);
    return (unsigned short)(u >> 16);
}
__device__ __forceinline__ float bf2f(unsigned short u) {
    return __uint_as_float(((unsigned int)u) << 16);
}
__device__ __forceinline__ float sigmoidf_(float x) { return 1.0f / (1.0f + expf(-x)); }
__device__ __forceinline__ float siluf_(float x)    { return x / (1.0f + expf(-x)); }

// global -> LDS direct copy, 16B/lane; lds base wave-uniform, lane l -> base+l*16B.
__device__ __forceinline__ void gload16(const unsigned short* g, unsigned short* l) {
    __builtin_amdgcn_global_load_lds(
        (const __attribute__((address_space(1))) unsigned int*)(const void*)g,
        (__attribute__((address_space(3))) unsigned int*)(void*)l,
        16, 0, 0);
}

#define VMW(n) asm volatile("s_waitcnt vmcnt(" #n ")" ::: "memory")

// XCD-aware swizzle of (bx,by) (R4-proven); requires gx*gy % 8 == 0 (guarded).
#define XCD_SWZ()                                                        \
    int bx = blockIdx.x, by = blockIdx.y;                                \
    {                                                                    \
        const int gx_ = gridDim.x;                                       \
        const int n_  = gx_ * gridDim.y;                                 \
        if ((n_ & 7) == 0) {                                             \
            int lin = by * gx_ + bx;                                     \
            const int q8 = n_ >> 3;                                      \
            lin = (lin & 7) * q8 + (lin >> 3);                           \
            bx = lin % gx_; by = lin / gx_;                              \
        }                                                                \
    }

// ===========================================================================
// mg_mega: ONE dispatch for skip|wi|wf|wo (K=4096) + q|k|v (24 head-mats,
// K=512). BM=256 x BN=128, 4 waves, wave tile 128x64, 2 LDS bufs (48KB),
// depth-1 counted-vmcnt, T21 XOR swizzle — inner loop identical to the
// R19/R20-proven mg256. Grid (224,4): col-blocks 0-127 big chunks,
// 128-223 qkv. All outputs ldc=4096; lda=4096 both paths.
// ===========================================================================
__global__ __launch_bounds__(256, 3) void mg_mega(
    const unsigned short* __restrict__ xconv, const unsigned short* __restrict__ xupL,
    const unsigned short* __restrict__ sT, const unsigned short* __restrict__ iT,
    const unsigned short* __restrict__ fT, const unsigned short* __restrict__ oT,
    const unsigned short* __restrict__ qkvT,
    const float* __restrict__ skip_b, const float* __restrict__ wi_b,
    const float* __restrict__ wf_b, const float* __restrict__ wo_b,
    const float* __restrict__ bq, const float* __restrict__ bk,
    const float* __restrict__ bv,
    unsigned short* __restrict__ xskip, float* __restrict__ itb,
    float* __restrict__ ftb, unsigned short* __restrict__ opb,
    float* __restrict__ qb, unsigned short* __restrict__ kb_bf,
    unsigned short* __restrict__ vb_bf, float kscale)
{
    // col-major XCD remap over 896 blocks
    const int gy = gridDim.y;
    const int n = gridDim.x * gy;
    const int orig = blockIdx.y * gridDim.x + blockIdx.x;
    const int wl = (orig & 7) * (n >> 3) + (orig >> 3);
    const int bxw = wl / gy;
    const int byw = wl - bxw * gy;

    const unsigned short *Ap, *Btp;
    const float* biasp;
    float* Cp = nullptr;
    unsigned short* C2p = nullptr;
    int Kloc, ldbt, rowBl;
    float alpha = 1.0f;
    bool bf16out;
    if (bxw < 128) {
        const int chid = bxw >> 5;
        rowBl = (bxw & 31) * 128;
        Kloc = 4096; ldbt = 4096;
        Ap = (chid == 3) ? xupL : xconv;
        Btp = (chid == 0) ? sT : (chid == 1) ? iT : (chid == 2) ? fT : oT;
        biasp = (chid == 0) ? skip_b : (chid == 1) ? wi_b : (chid == 2) ? wf_b : wo_b;
        bf16out = (chid == 0) || (chid == 3);
        C2p = (chid == 0) ? xskip : opb;
        Cp  = (chid == 1) ? itb : ftb;
    } else {
        const int j = bxw - 128;
        const int mat = j >> 2;              // 0..23
        rowBl = (j & 3) * 128;
        const int sel = mat >> 3, head = mat & 7;
        Kloc = 512; ldbt = 512;
        Ap = ((sel == 2) ? xupL : xconv) + head * 512;
        Btp = qkvT + (long)mat * (HS * HS);
        biasp = ((sel == 0) ? bq : (sel == 1) ? bk : bv) + head * 512;
        alpha = (sel == 1) ? kscale : 1.0f;
        bf16out = (sel != 0);
        Cp  = qb + head * 512;
        C2p = ((sel == 1) ? kb_bf : vb_bf) + head * 512;
    }

    __shared__ __align__(16) unsigned short As[2][256][32];
    __shared__ __align__(16) unsigned short Bs[2][128][32];

    const int t = threadIdx.x;
    const int w = t >> 6, l = t & 63;
    const int wrm = w >> 1;
    const int wcn = w & 1;
    const long rowA = (long)byw * 256;

    const int skz = (((l & 3) ^ ((l >> 3) & 3)) << 3);
    const unsigned short* Ag = Ap  + rowA * 4096L;
    const unsigned short* Bg = Btp + (long)rowBl * ldbt;

    const int lm  = l & 15;
    const int pkz = (((l >> 4) ^ ((l >> 1) & 3)) << 3);

    f32x4_t acc[8][4];
#pragma unroll
    for (int mi = 0; mi < 8; ++mi)
#pragma unroll
        for (int ni = 0; ni < 4; ++ni) acc[mi][ni] = (f32x4_t)0.0f;

#define STAGE(buf, kb)                                                        \
    {                                                                         \
        _Pragma("unroll")                                                     \
        for (int p = 0; p < 4; ++p)                                           \
            gload16(Ag + (long)(w * 64 + p * 16 + (l >> 2)) * 4096 + (kb) + skz, \
                    &As[buf][w * 64 + p * 16][0]);                            \
        _Pragma("unroll")                                                     \
        for (int p = 0; p < 2; ++p)                                           \
            gload16(Bg + (long)(w * 32 + p * 16 + (l >> 2)) * ldbt + (kb) + skz, \
                    &Bs[buf][w * 32 + p * 16][0]);                            \
    }

    const int nsteps = Kloc >> 5;
    STAGE(0, 0);

    int cur = 0;
    for (int ti = 0; ti < nsteps; ++ti) {
        if (ti + 1 < nsteps) {
            STAGE(cur ^ 1, (ti + 1) << 5);
            VMW(6);
        } else {
            VMW(0);
        }
        __builtin_amdgcn_s_barrier();

        bf16x8_t bfr[4];
#pragma unroll
        for (int ni = 0; ni < 4; ++ni)
            bfr[ni] = *(const bf16x8_t*)&Bs[cur][wcn * 64 + ni * 16 + lm][pkz];
#pragma unroll
        for (int mi = 0; mi < 8; ++mi) {
            const bf16x8_t af = *(const bf16x8_t*)&As[cur][wrm * 128 + mi * 16 + lm][pkz];
#pragma unroll
            for (int ni = 0; ni < 4; ++ni)
                acc[mi][ni] = __builtin_amdgcn_mfma_f32_16x16x32_bf16(
                    af, bfr[ni], acc[mi][ni], 0, 0, 0);
        }

        asm volatile("s_waitcnt lgkmcnt(0)" ::: "memory");
        __builtin_amdgcn_s_barrier();
        cur ^= 1;
    }
#undef STAGE

    // C/D layout: col = lane&15, row = (lane>>4)*4 + reg
    const int lr4 = (l >> 4) * 4;
#pragma unroll
    for (int mi = 0; mi < 8; ++mi) {
        const long m0 = rowA + wrm * 128 + mi * 16 + lr4;
#pragma unroll
        for (int ni = 0; ni < 4; ++ni) {
            const int nn = rowBl + wcn * 64 + ni * 16 + lm;
            const float bv4 = biasp[nn];
#pragma unroll
            for (int r = 0; r < 4; ++r) {
                const float v = (acc[mi][ni][r] + bv4) * alpha;
                const long m = m0 + r;
                if (bf16out) C2p[m * 4096 + nn] = f2bf(v);
                else         Cp [m * 4096 + nn] = v;
            }
        }
    }
}

// ===========================================================================
// mg256 (chunked, kept for denom epi3 + generic): proven R19/R20 body.
// epi: 0 f32, 2 f32*alpha, 3 abs-row-max->denom, 5 bf16.
// ===========================================================================
struct MGChunk {
    const unsigned short* A;
    const unsigned short* Bt;
    const float* bias;
    const float* resid;
    float* C;
    unsigned short* C2;
    float* denom;
    float alpha;
    int epi;
};

template<int NCH>
__global__ __launch_bounds__(256, 3) void mg256(
    MGChunk c0, MGChunk c1, MGChunk c2, MGChunk c3,
    int K, int lda, int ldbt, int ldc, int bpc,
    long aB, long wB, long bB, long cB)
{
    const int gx = gridDim.x, gy = gridDim.y;
    const int n = gx * gy;
    const int orig = blockIdx.y * gx + blockIdx.x;
    const int wl = ((n & 7) == 0) ? ((orig & 7) * (n >> 3) + (orig >> 3)) : orig;
    const int bxw = wl / gy;
    const int byw = wl - bxw * gy;
    const int chid = (NCH > 1) ? (bxw / bpc) : 0;
    const int cbx = bxw - chid * bpc;
    const MGChunk ch = (chid == 0) ? c0 : ((chid == 1) ? c1 : ((chid == 2) ? c2 : c3));
    const int bz = blockIdx.z;

    const unsigned short* A  = ch.A  + bz * aB;
    const unsigned short* Bt = ch.Bt + bz * wB;

    __shared__ __align__(16) unsigned short As[2][256][32];
    __shared__ __align__(16) unsigned short Bs[2][128][32];

    const int t = threadIdx.x;
    const int w = t >> 6, l = t & 63;
    const int wrm = w >> 1;
    const int wcn = w & 1;
    const long rowA = (long)byw * 256;
    const long rowB = (long)cbx * 128;

    const int skz = (((l & 3) ^ ((l >> 3) & 3)) << 3);
    const unsigned short* Ag = A  + rowA * (long)lda;
    const unsigned short* Bg = Bt + rowB * (long)ldbt;

    const int lm  = l & 15;
    const int pkz = (((l >> 4) ^ ((l >> 1) & 3)) << 3);

    f32x4_t acc[8][4];
#pragma unroll
    for (int mi = 0; mi < 8; ++mi)
#pragma unroll
        for (int ni = 0; ni < 4; ++ni) acc[mi][ni] = (f32x4_t)0.0f;

#define STAGE(buf, kb)                                                        \
    {                                                                         \
        _Pragma("unroll")                                                     \
        for (int p = 0; p < 4; ++p)                                           \
            gload16(Ag + (long)(w * 64 + p * 16 + (l >> 2)) * lda + (kb) + skz, \
                    &As[buf][w * 64 + p * 16][0]);                            \
        _Pragma("unroll")                                                     \
        for (int p = 0; p < 2; ++p)                                           \
            gload16(Bg + (long)(w * 32 + p * 16 + (l >> 2)) * ldbt + (kb) + skz, \
                    &Bs[buf][w * 32 + p * 16][0]);                            \
    }

    const int nsteps = K >> 5;
    STAGE(0, 0);

    int cur = 0;
    for (int ti = 0; ti < nsteps; ++ti) {
        if (ti + 1 < nsteps) {
            STAGE(cur ^ 1, (ti + 1) << 5);
            VMW(6);
        } else {
            VMW(0);
        }
        __builtin_amdgcn_s_barrier();

        bf16x8_t bfr[4];
#pragma unroll
        for (int ni = 0; ni < 4; ++ni)
            bfr[ni] = *(const bf16x8_t*)&Bs[cur][wcn * 64 + ni * 16 + lm][pkz];
#pragma unroll
        for (int mi = 0; mi < 8; ++mi) {
            const bf16x8_t af = *(const bf16x8_t*)&As[cur][wrm * 128 + mi * 16 + lm][pkz];
#pragma unroll
            for (int ni = 0; ni < 4; ++ni)
                acc[mi][ni] = __builtin_amdgcn_mfma_f32_16x16x32_bf16(
                    af, bfr[ni], acc[mi][ni], 0, 0, 0);
        }

        asm volatile("s_waitcnt lgkmcnt(0)" ::: "memory");
        __builtin_amdgcn_s_barrier();
        cur ^= 1;
    }
#undef STAGE

    const int lr4 = (l >> 4) * 4;
    if (ch.epi == 3) {
        float rmax[8][4];
#pragma unroll
        for (int mi = 0; mi < 8; ++mi)
#pragma unroll
            for (int r = 0; r < 4; ++r) {
                float m = 0.0f;
#pragma unroll
                for (int ni = 0; ni < 4; ++ni) m = fmaxf(m, fabsf(acc[mi][ni][r]));
                rmax[mi][r] = m;
            }
#pragma unroll
        for (int off = 1; off < 16; off <<= 1)
#pragma unroll
            for (int mi = 0; mi < 8; ++mi)
#pragma unroll
                for (int r = 0; r < 4; ++r)
                    rmax[mi][r] = fmaxf(rmax[mi][r], __shfl_xor(rmax[mi][r], off, 64));
        if (lm == 0) {
#pragma unroll
            for (int mi = 0; mi < 8; ++mi)
#pragma unroll
                for (int r = 0; r < 4; ++r) {
                    const long m = rowA + wrm * 128 + mi * 16 + lr4 + r;
                    atomicMax((unsigned int*)&ch.denom[m], __float_as_uint(rmax[mi][r]));
                }
        }
        return;
    }
    const float* bias = ch.bias + bz * bB;
#pragma unroll
    for (int mi = 0; mi < 8; ++mi) {
        const long m0 = rowA + wrm * 128 + mi * 16 + lr4;
#pragma unroll
        for (int ni = 0; ni < 4; ++ni) {
            const long nn = rowB + wcn * 64 + ni * 16 + lm;
            const float bv = bias[nn];
#pragma unroll
            for (int r = 0; r < 4; ++r) {
                float v = acc[mi][ni][r] + bv;
                if (ch.epi == 2) v *= ch.alpha;
                const long m = m0 + r;
                if (ch.epi == 5) (ch.C2 + bz * cB)[m * ldc + nn] = f2bf(v);
                else             (ch.C  + bz * cB)[m * ldc + nn] = v;
            }
        }
    }
}

// ===========================================================================
// mgemm_mc: R4-proven reg-staged double-buffered 128x128 multi-chunk GEMM.
// epi: 0 = f32 out; 5 = bf16 out.
// ===========================================================================
struct MCChunk {
    const unsigned short* A;
    const unsigned short* Bt;
    const float* bias;
    float* C;
    unsigned short* C2;
    float alpha;
    int epi;
};

template<int NCH>
__global__ __launch_bounds__(256) void mgemm_mc(
    MCChunk c0, MCChunk c1, MCChunk c2,
    int K, int lda, int ldbt, int ldc, int bpc,
    long aB, long wB, long bB, long cB)
{
    XCD_SWZ();
    const int chid = bx / bpc;
    const int cbx  = bx - chid * bpc;
    const MCChunk ch = (chid == 0) ? c0 : ((NCH > 1 && chid == 1) ? c1 : c2);
    const int bz = blockIdx.z;

    const unsigned short* A  = ch.A  + bz * aB;
    const unsigned short* Bt = ch.Bt + bz * wB;
    const float* bias = ch.bias + bz * bB;

    __shared__ __align__(16) unsigned short As[2][128][40];
    __shared__ __align__(16) unsigned short Bs[2][128][40];

    const int t = threadIdx.x;
    const int w = t >> 6, l = t & 63;
    const int wr = w >> 1, wc = w & 1;
    const long rowA = (long)by * 128;
    const long rowB = (long)cbx * 128;

    const int lr = t >> 2;
    const int lc = (t & 3) << 3;
    const unsigned short* Ag = A  + (rowA + lr) * (long)lda  + lc;
    const unsigned short* Bg = Bt + (rowB + lr) * (long)ldbt + lc;

    const int lm = l & 15;
    const int lk = (l >> 4) * 8;

    f32x4_t acc[4][4];
#pragma unroll
    for (int mi = 0; mi < 4; ++mi)
#pragma unroll
        for (int ni = 0; ni < 4; ++ni) acc[mi][ni] = (f32x4_t)0.0f;

    bf16x8_t ra[2], rb[2];
#pragma unroll
    for (int p = 0; p < 2; ++p) {
        ra[p] = *(const bf16x8_t*)(Ag + (long)p * 64 * lda);
        rb[p] = *(const bf16x8_t*)(Bg + (long)p * 64 * ldbt);
    }
#pragma unroll
    for (int p = 0; p < 2; ++p) {
        *(bf16x8_t*)&As[0][lr + p * 64][lc] = ra[p];
        *(bf16x8_t*)&Bs[0][lr + p * 64][lc] = rb[p];
    }
    __syncthreads();

    const int nsteps = K >> 5;
    for (int ti = 0; ti < nsteps; ++ti) {
        const int cur = ti & 1;
        if (ti + 1 < nsteps) {
            const int kb = (ti + 1) << 5;
#pragma unroll
            for (int p = 0; p < 2; ++p) {
                ra[p] = *(const bf16x8_t*)(Ag + (long)p * 64 * lda  + kb);
                rb[p] = *(const bf16x8_t*)(Bg + (long)p * 64 * ldbt + kb);
            }
        }
        bf16x8_t af[4], bfr[4];
#pragma unroll
        for (int mi = 0; mi < 4; ++mi)
            af[mi] = *(const bf16x8_t*)&As[cur][wr * 64 + mi * 16 + lm][lk];
#pragma unroll
        for (int ni = 0; ni < 4; ++ni)
            bfr[ni] = *(const bf16x8_t*)&Bs[cur][wc * 64 + ni * 16 + lm][lk];
#pragma unroll
        for (int mi = 0; mi < 4; ++mi)
#pragma unroll
            for (int ni = 0; ni < 4; ++ni)
                acc[mi][ni] = __builtin_amdgcn_mfma_f32_16x16x32_bf16(
                    af[mi], bfr[ni], acc[mi][ni], 0, 0, 0);
        if (ti + 1 < nsteps) {
            const int nxt = cur ^ 1;
#pragma unroll
            for (int p = 0; p < 2; ++p) {
                *(bf16x8_t*)&As[nxt][lr + p * 64][lc] = ra[p];
                *(bf16x8_t*)&Bs[nxt][lr + p * 64][lc] = rb[p];
            }
        }
        __syncthreads();
    }

    const int lr4 = (l >> 4) * 4;
    const float alpha = ch.alpha;
#pragma unroll
    for (int mi = 0; mi < 4; ++mi) {
        const long m0 = rowA + wr * 64 + mi * 16 + lr4;
#pragma unroll
        for (int ni = 0; ni < 4; ++ni) {
            const long nn = rowB + wc * 64 + ni * 16 + lm;
            const float bv = bias[nn];
#pragma unroll
            for (int r = 0; r < 4; ++r) {
                const float v = (acc[mi][ni][r] + bv) * alpha;
                const long m = m0 + r;
                if (ch.epi == 5) (ch.C2 + bz * cB)[m * ldc + nn] = f2bf(v);
                else             (ch.C  + bz * cB)[m * ldc + nn] = v;
            }
        }
    }
}

// ===========================================================================
// mgemm: R4-proven single-chunk reg-staged GEMM. EPI 4 = f32 acc+bias+resid.
// ===========================================================================
template<int BM, int EPI>
__global__ __launch_bounds__(256) void mgemm(
    const unsigned short* __restrict__ A, const unsigned short* __restrict__ Bt,
    const float* __restrict__ bias, const float* __restrict__ resid,
    float* __restrict__ C, float* __restrict__ denom,
    int K, int lda, int ldbt, int ldc)
{
    constexpr int MR = BM / 32;
    constexpr int AP = BM / 64;
    XCD_SWZ();

    __shared__ __align__(16) unsigned short As[2][BM][40];
    __shared__ __align__(16) unsigned short Bs[2][128][40];

    const int t = threadIdx.x;
    const int w = t >> 6, l = t & 63;
    const int wr = w >> 1, wc = w & 1;
    const long rowA = (long)by * BM;
    const long rowB = (long)bx * 128;

    const int lr = t >> 2;
    const int lc = (t & 3) << 3;
    const unsigned short* Ag = A  + (rowA + lr) * (long)lda  + lc;
    const unsigned short* Bg = Bt + (rowB + lr) * (long)ldbt + lc;

    const int lm = l & 15;
    const int lk = (l >> 4) * 8;

    f32x4_t acc[MR][4];
#pragma unroll
    for (int mi = 0; mi < MR; ++mi)
#pragma unroll
        for (int ni = 0; ni < 4; ++ni) acc[mi][ni] = (f32x4_t)0.0f;

    bf16x8_t ra[AP], rb[2];
#pragma unroll
    for (int p = 0; p < AP; ++p) ra[p] = *(const bf16x8_t*)(Ag + (long)p * 64 * lda);
#pragma unroll
    for (int p = 0; p < 2;  ++p) rb[p] = *(const bf16x8_t*)(Bg + (long)p * 64 * ldbt);
#pragma unroll
    for (int p = 0; p < AP; ++p) *(bf16x8_t*)&As[0][lr + p * 64][lc] = ra[p];
#pragma unroll
    for (int p = 0; p < 2;  ++p) *(bf16x8_t*)&Bs[0][lr + p * 64][lc] = rb[p];
    __syncthreads();

    const int nsteps = K >> 5;
    for (int ti = 0; ti < nsteps; ++ti) {
        const int cur = ti & 1;
        if (ti + 1 < nsteps) {
            const int kb = (ti + 1) << 5;
#pragma unroll
            for (int p = 0; p < AP; ++p) ra[p] = *(const bf16x8_t*)(Ag + (long)p * 64 * lda  + kb);
#pragma unroll
            for (int p = 0; p < 2;  ++p) rb[p] = *(const bf16x8_t*)(Bg + (long)p * 64 * ldbt + kb);
        }
        bf16x8_t af[MR], bfr[4];
#pragma unroll
        for (int mi = 0; mi < MR; ++mi)
            af[mi] = *(const bf16x8_t*)&As[cur][wr * (BM / 2) + mi * 16 + lm][lk];
#pragma unroll
        for (int ni = 0; ni < 4; ++ni)
            bfr[ni] = *(const bf16x8_t*)&Bs[cur][wc * 64 + ni * 16 + lm][lk];
#pragma unroll
        for (int mi = 0; mi < MR; ++mi)
#pragma unroll
            for (int ni = 0; ni < 4; ++ni)
                acc[mi][ni] = __builtin_amdgcn_mfma_f32_16x16x32_bf16(
                    af[mi], bfr[ni], acc[mi][ni], 0, 0, 0);
        if (ti + 1 < nsteps) {
            const int nxt = cur ^ 1;
#pragma unroll
            for (int p = 0; p < AP; ++p) *(bf16x8_t*)&As[nxt][lr + p * 64][lc] = ra[p];
#pragma unroll
            for (int p = 0; p < 2;  ++p) *(bf16x8_t*)&Bs[nxt][lr + p * 64][lc] = rb[p];
        }
        __syncthreads();
    }

    const int lr4 = (l >> 4) * 4;
#pragma unroll
    for (int mi = 0; mi < MR; ++mi) {
        const long m0 = rowA + wr * (BM / 2) + mi * 16 + lr4;
#pragma unroll
        for (int ni = 0; ni < 4; ++ni) {
            const long nn = rowB + wc * 64 + ni * 16 + lm;
            const float bv = bias[nn];
#pragma unroll
            for (int r = 0; r < 4; ++r) {
                float v = acc[mi][ni][r] + bv;
                const long m = m0 + r;
                if (EPI == 4) v += resid[m * ldc + nn];
                C[m * ldc + nn] = v;
            }
        }
    }
}

// ---------------------------------------------------------------------------
// Batched transpose + f32->bf16 (16B/lane stores, R18-proven).
// ---------------------------------------------------------------------------
struct TP4 {
    const float* s0; const float* s1; const float* s2; const float* s3;
    unsigned short* d0; unsigned short* d1; unsigned short* d2; unsigned short* d3;
};

__global__ __launch_bounds__(256) void tp_batch(TP4 tp, int R, int C)
{
    const int z = blockIdx.z;
    const float* X = (z == 0) ? tp.s0 : (z == 1) ? tp.s1 : (z == 2) ? tp.s2 : tp.s3;
    unsigned short* XT = (z == 0) ? tp.d0 : (z == 1) ? tp.d1 : (z == 2) ? tp.d2 : tp.d3;
    __shared__ float tile[64][65];
    const int t = threadIdx.x;
    const long r0 = (long)blockIdx.y * 64;
    const long c0 = (long)blockIdx.x * 64;
    const int tr = t >> 4;
    const int tc = (t & 15) << 2;
#pragma unroll
    for (int p = 0; p < 4; ++p) {
        const float4 v = *(const float4*)(X + (r0 + tr + p * 16) * C + c0 + tc);
        tile[tr + p * 16][tc + 0] = v.x;
        tile[tr + p * 16][tc + 1] = v.y;
        tile[tr + p * 16][tc + 2] = v.z;
        tile[tr + p * 16][tc + 3] = v.w;
    }
    __syncthreads();
#pragma unroll
    for (int p = 0; p < 2; ++p) {
        const int orow = (t >> 3) + p * 32;
        const int oc8  = (t & 7) * 8;
        unsigned short tmp[8];
#pragma unroll
        for (int j = 0; j < 8; ++j) tmp[j] = f2bf(tile[oc8 + j][orow]);
        *(bf16x8_t*)(XT + (c0 + orow) * (long)R + r0 + oc8) = *(const bf16x8_t*)tmp;
    }
}

// qkv weights: (NH,HS,HS) f32 x3 -> concatenated (3,NH,HS,HS) bf16 transposed
__global__ __launch_bounds__(256) void tp_qkv(
    const float* wq, const float* wk, const float* wv, unsigned short* dst)
{
    const int z = blockIdx.z;
    const int sel = z >> 3, head = z & 7;
    const float* X = ((sel == 0) ? wq : (sel == 1) ? wk : wv) + (long)head * HS * HS;
    unsigned short* XT = dst + (long)sel * NH * HS * HS + (long)head * HS * HS;
    __shared__ float tile[64][65];
    const int t = threadIdx.x;
    const long r0 = (long)blockIdx.y * 64;
    const long c0 = (long)blockIdx.x * 64;
    const int tr = t >> 4;
    const int tc = (t & 15) << 2;
#pragma unroll
    for (int p = 0; p < 4; ++p) {
        const float4 v = *(const float4*)(X + (r0 + tr + p * 16) * HS + c0 + tc);
        tile[tr + p * 16][tc + 0] = v.x;
        tile[tr + p * 16][tc + 1] = v.y;
        tile[tr + p * 16][tc + 2] = v.z;
        tile[tr + p * 16][tc + 3] = v.w;
    }
    __syncthreads();
#pragma unroll
    for (int p = 0; p < 2; ++p) {
        const int orow = (t >> 3) + p * 32;
        const int oc8  = (t & 7) * 8;
        unsigned short tmp[8];
#pragma unroll
        for (int j = 0; j < 8; ++j) tmp[j] = f2bf(tile[oc8 + j][orow]);
        *(bf16x8_t*)(XT + (c0 + orow) * (long)HS + r0 + oc8) = *(const bf16x8_t*)tmp;
    }
}

// ---------------------------------------------------------------------------
// LayerNorm over D_IN per row -> bf16
// ---------------------------------------------------------------------------
__global__ __launch_bounds__(256) void layernorm_kernel(
    const float* __restrict__ x, const float* __restrict__ w,
    const float* __restrict__ b, unsigned short* __restrict__ out)
{
    __shared__ float sh[8];
    const int row = blockIdx.x, t = threadIdx.x;
    const float* xr = x + (long)row * D_IN;
    float v[8];
    float s = 0.f, ss = 0.f;
#pragma unroll
    for (int i = 0; i < 8; ++i) {
        v[i] = xr[t + 256 * i];
        s += v[i];
        ss += v[i] * v[i];
    }
#pragma unroll
    for (int off = 32; off; off >>= 1) {
        s  += __shfl_down(s, off, 64);
        ss += __shfl_down(ss, off, 64);
    }
    const int lane = t & 63, wid = t >> 6;
    if (lane == 0) { sh[wid * 2] = s; sh[wid * 2 + 1] = ss; }
    __syncthreads();
    s = 0.f; ss = 0.f;
#pragma unroll
    for (int i = 0; i < 4; ++i) { s += sh[i * 2]; ss += sh[i * 2 + 1]; }
    const float mu  = s * (1.0f / D_IN);
    const float var = ss * (1.0f / D_IN) - mu * mu;
    const float rs  = rsqrtf(var + LN_EPS);
    unsigned short* orow = out + (long)row * D_IN;
#pragma unroll
    for (int i = 0; i < 8; ++i) {
        const int d = t + 256 * i;
        orow[d] = f2bf((v[i] - mu) * rs * w[d] + b[d]);
    }
}

// ---------------------------------------------------------------------------
// Causal conv1d (K=4, left pad 3) + SiLU.  bf16 -> bf16
// ---------------------------------------------------------------------------
__global__ void conv_silu_kernel(const unsigned short* __restrict__ xl,
                                 const float* __restrict__ cw,
                                 const float* __restrict__ cb,
                                 unsigned short* __restrict__ out)
{
    const long idx = (long)blockIdx.x * blockDim.x + threadIdx.x;
    if (idx >= (long)B_ROWS * D_UP) return;
    const int d = (int)(idx & (D_UP - 1));
    const float w0 = cw[0], w1 = cw[1], w2 = cw[2], w3 = cw[3];
    float acc = cb[0] + w3 * bf2f(xl[idx]);
    if (d >= 1) acc += w2 * bf2f(xl[idx - 1]);
    if (d >= 2) acc += w1 * bf2f(xl[idx - 2]);
    if (d >= 3) acc += w0 * bf2f(xl[idx - 3]);
    out[idx] = f2bf(siluf_(acc));
}

// ---------------------------------------------------------------------------
// Stabilized exponential gating; k,v read as bf16 -> m_t, c_t, n_t
// ---------------------------------------------------------------------------
__global__ void gating_kernel(const float4* __restrict__ it, const float4* __restrict__ ft,
                              const float4* __restrict__ mp, const float4* __restrict__ cp,
                              const float4* __restrict__ np_, const us4_t* __restrict__ kk,
                              const us4_t* __restrict__ vv,
                              float4* __restrict__ mt, float4* __restrict__ ct,
                              float4* __restrict__ nt)
{
    const long idx = (long)blockIdx.x * blockDim.x + threadIdx.x;
    if (idx >= (long)B_ROWS * D_HID / 4) return;
    const float4 i4 = it[idx], f4 = ft[idx], mp4 = mp[idx];
    const float4 cp4 = cp[idx], np4 = np_[idx];
    const us4_t k4 = kk[idx], v4 = vv[idx];
    float4 m4, c4, n4;
#pragma unroll
    for (int j = 0; j < 4; ++j) {
        const float i_t = (&i4.x)[j];
        const float f_t = (&f4.x)[j] + (&mp4.x)[j];
        const float m_t = fmaxf(f_t, i_t);
        const float i_g = expf(i_t - m_t);
        const float f_g = expf(f_t - m_t);
        const float kv  = bf2f(k4[j]);
        (&c4.x)[j] = f_g * (&cp4.x)[j] + i_g * (bf2f(v4[j]) * kv);
        (&n4.x)[j] = f_g * (&np4.x)[j] + i_g * kv;
        (&m4.x)[j] = m_t;
    }
    ct[idx] = c4;
    nt[idx] = n4;
    mt[idx] = m4;
}

// ---------------------------------------------------------------------------
// Fused: h_t = sigmoid(op)*c_t*q/denom  +  GroupNorm + skip + silu-gate
// ---------------------------------------------------------------------------
__global__ __launch_bounds__(128) void hgnorm_kernel(
    const unsigned short* __restrict__ op, const float* __restrict__ ct,
    const float* __restrict__ qb, const float* __restrict__ denom,
    const float* __restrict__ gw, const float* __restrict__ gb,
    const unsigned short* __restrict__ xskip, const unsigned short* __restrict__ xupR,
    float* __restrict__ ht, unsigned short* __restrict__ out)
{
    __shared__ float sh[4];
    const int b = blockIdx.x >> 3, h = blockIdx.x & 7;
    const int t = threadIdx.x;
    const long base = (long)b * D_HID + h * HS;
    float v[4];
    float s = 0.f, ss = 0.f;
#pragma unroll
    for (int i = 0; i < 4; ++i) {
        const long ix = base + t + 128 * i;
        const int  dg = h * HS + t + 128 * i;
        const float hv = sigmoidf_(bf2f(op[ix])) * ct[ix] * qb[ix] / denom[dg];
        ht[ix] = hv;
        v[i] = hv;
        s += hv;
        ss += hv * hv;
    }
#pragma unroll
    for (int off = 32; off; off >>= 1) {
        s  += __shfl_down(s, off, 64);
        ss += __shfl_down(ss, off, 64);
    }
    if ((t & 63) == 0) { sh[(t >> 6) * 2] = s; sh[(t >> 6) * 2 + 1] = ss; }
    __syncthreads();
    s = sh[0] + sh[2];
    ss = sh[1] + sh[3];
    const float mu  = s * (1.0f / HS);
    const float var = ss * (1.0f / HS) - mu * mu;
    const float rs  = rsqrtf(var + LN_EPS);
#pragma unroll
    for (int i = 0; i < 4; ++i) {
        const int  dg = h * HS + t + 128 * i;
        const long ix = base + t + 128 * i;
        const float g = (v[i] - mu) * rs * gw[dg] + gb[dg];
        out[ix] = f2bf((g + bf2f(xskip[ix])) * siluf_(bf2f(xupR[ix])));
    }
}

// ---------------------------------------------------------------------------
extern "C" void kernel_launch(void* const* d_in, const int* in_sizes, int n_in,
                              void* d_out, int out_size, void* d_ws, size_t ws_size,
                              hipStream_t stream)
{
    const float* x      = (const float*)d_in[0];
    const float* c_prev = (const float*)d_in[2];
    const float* n_prev = (const float*)d_in[3];
    const float* m_prev = (const float*)d_in[4];
    const float* ln_w   = (const float*)d_in[5];
    const float* ln_b   = (const float*)d_in[6];
    const float* upL_w  = (const float*)d_in[7];
    const float* upL_b  = (const float*)d_in[8];
    const float* upR_w  = (const float*)d_in[9];
    const float* upR_b  = (const float*)d_in[10];
    const float* conv_w = (const float*)d_in[11];
    const float* conv_b = (const float*)d_in[12];
    const float* skip_w = (const float*)d_in[13];
    const float* skip_b = (const float*)d_in[14];
    const float* wq     = (const float*)d_in[15];
    const float* bq     = (const float*)d_in[16];
    const float* wk     = (const float*)d_in[17];
    const float* bk     = (const float*)d_in[18];
    const float* wv     = (const float*)d_in[19];
    const float* bv     = (const float*)d_in[20];
    const float* wi_w   = (const float*)d_in[21];
    const float* wi_b   = (const float*)d_in[22];
    const float* wf_w   = (const float*)d_in[23];
    const float* wf_b   = (const float*)d_in[24];
    const float* wo_w   = (const float*)d_in[25];
    const float* wo_b   = (const float*)d_in[26];
    const float* gn_w   = (const float*)d_in[27];
    const float* gn_b   = (const float*)d_in[28];
    const float* down_w = (const float*)d_in[29];
    const float* down_b = (const float*)d_in[30];

    float* out     = (float*)d_out;
    float* final_o = out;                       // [0, 2M) f32
    float* ht      = final_o + 2097152;         // [2M, 6M)
    float* ct      = ht + 4194304;              // [6M, 10M)
    float* nt      = ct + 4194304;              // [10M, 14M)
    float* mt      = nt + 4194304;              // [14M, 18M)

    // d_out scratch: WTA = ht+ct (skip^T), WTB = nt+mt (wi^T); consumed by
    // mega before gating writes those regions (stream-serial).
    unsigned short* WTA = (unsigned short*)ht;
    unsigned short* WTB = (unsigned short*)nt;

    // ---- ws layout (fl = float units; M = 1M fl). Peak = 47M fl < 47.2M proven.
    // [0,8M)  wo^T (WTD)             live step5..mega
    // [8,10M) kb_bf                  mega..gating ; then tmp_bf step11..12
    // [10,12M) vb_bf                 mega..gating
    // [12,16M) itb f32               mega..gating ; then dwT step10..12
    // [16,20M) ftb f32               mega..gating
    // [20,22M) xupR_bf               step3..11
    // [22,24M) xskip_bf              mega..11
    // [24,26M) opb_bf                mega..11
    // [26,27M) xnorm_bf              step1..3 ; ntT [26,28M) step9 (xupL dead)
    // [27,29M) xupL_bf               step3..mega ; qT [28,30M) step9
    // [29,31M) xconv_bf              step4..mega
    // [31M)    denom (4096 f32)
    // [32,40M) wf^T (WTC)            step5..mega
    // [40,43M) qkvT                  step5..mega
    // [43,47M) qb f32                mega..step11
    const long M = 1048576;
    float* ws = (float*)d_ws;
    unsigned short* WTD      = (unsigned short*)(ws +  0 * M);
    unsigned short* kb_bf    = (unsigned short*)(ws +  8 * M);
    unsigned short* vb_bf    = (unsigned short*)(ws + 10 * M);
    float* itb = ws + 12 * M;
    float* ftb = ws + 16 * M;
    unsigned short* xupR_bf  = (unsigned short*)(ws + 20 * M);
    unsigned short* xskip_bf = (unsigned short*)(ws + 22 * M);
    unsigned short* opb_bf   = (unsigned short*)(ws + 24 * M);
    unsigned short* xnorm_bf = (unsigned short*)(ws + 26 * M);
    unsigned short* xupL_bf  = (unsigned short*)(ws + 27 * M);
    unsigned short* xconv_bf = (unsigned short*)(ws + 29 * M);
    float* denom             = ws + 31 * M;
    unsigned short* WTC      = (unsigned short*)(ws + 32 * M);
    unsigned short* qkvT     = (unsigned short*)(ws + 40 * M);
    float* qb                = ws + 43 * M;
    unsigned short* ntT      = (unsigned short*)(ws + 26 * M);
    unsigned short* qT       = (unsigned short*)(ws + 28 * M);
    unsigned short* dwT      = (unsigned short*)(ws + 12 * M);
    unsigned short* tmp_bf   = (unsigned short*)(ws +  8 * M);

    const float kscale = 1.0f / sqrtf((float)HS);
    MGChunk cz = {};
    MCChunk mz = {};

    // 1. LayerNorm -> bf16
    layernorm_kernel<<<B_ROWS, 256, 0, stream>>>(x, ln_w, ln_b, xnorm_bf);

    // 2. upL^T, upR^T -> WTA
    {
        TP4 tp = { upL_w, upR_w, nullptr, nullptr, WTA, WTA + 8388608, nullptr, nullptr };
        tp_batch<<<dim3(64, 32, 2), 256, 0, stream>>>(tp, D_IN, D_UP);
    }
    // 3. upL | upR GEMM (R4-proven mgemm_mc, grid 512)
    {
        MCChunk a = { xnorm_bf, WTA,           upL_b, nullptr, xupL_bf, 1.0f, 5 };
        MCChunk b = { xnorm_bf, WTA + 8388608, upR_b, nullptr, xupR_bf, 1.0f, 5 };
        mgemm_mc<2><<<dim3(64, 8, 1), 256, 0, stream>>>(
            a, b, mz, D_IN, D_IN, D_IN, D_HID, 32, 0, 0, 0, 0);
    }

    // 4. causal conv + silu -> bf16
    conv_silu_kernel<<<(B_ROWS * D_UP) / 256, 256, 0, stream>>>(xupL_bf, conv_w, conv_b, xconv_bf);

    // 5. weight transposes: skip^T->WTA, wi^T->WTB, wf^T->WTC, wo^T->WTD; qkv^T->qkvT
    {
        TP4 tp = { skip_w, wi_w, wf_w, wo_w, WTA, WTB, WTC, WTD };
        tp_batch<<<dim3(64, 64, 4), 256, 0, stream>>>(tp, D_UP, D_HID);
    }
    tp_qkv<<<dim3(8, 8, 24), 256, 0, stream>>>(wq, wk, wv, qkvT);

    // 6. MEGA: skip|wi|wf|wo + q|k|v in ONE dispatch (grid 224x4 = 896 blocks)
    mg_mega<<<dim3(224, 4, 1), 256, 0, stream>>>(
        xconv_bf, xupL_bf, WTA, WTB, WTC, WTD, qkvT,
        skip_b, wi_b, wf_b, wo_b, bq, bk, bv,
        xskip_bf, itb, ftb, opb_bf, qb, kb_bf, vb_bf, kscale);

    // 7. gating (bf16 k/v) -> m_t, c_t, n_t
    gating_kernel<<<(B_ROWS * D_HID / 4) / 256, 256, 0, stream>>>(
        (const float4*)itb, (const float4*)ftb, (const float4*)m_prev,
        (const float4*)c_prev, (const float4*)n_prev, (const us4_t*)kb_bf,
        (const us4_t*)vb_bf, (float4*)mt, (float4*)ct, (float4*)nt);

    // 8. nt^T, q^T -> ntT/qT; denom = rowwise max |n_t^T q| via mg256 epi3
    {
        TP4 tp = { nt, qb, nullptr, nullptr, ntT, qT, nullptr, nullptr };
        tp_batch<<<dim3(64, 16, 2), 256, 0, stream>>>(tp, B_ROWS, D_HID);
    }
    hipMemsetAsync(denom, 0, D_HID * sizeof(float), stream);
    {
        MGChunk a = { ntT, qT, nullptr, nullptr, nullptr, nullptr, denom, 1.0f, 3 };
        mg256<1><<<dim3(32, 16, 1), 256, 0, stream>>>(
            a, cz, cz, cz, B_ROWS, B_ROWS, B_ROWS, 0, 32, 0, 0, 0, 0);
    }

    // 9. down^T -> dwT (itb region, dead after gating)
    {
        TP4 tp = { down_w, nullptr, nullptr, nullptr, dwT, nullptr, nullptr, nullptr };
        tp_batch<<<dim3(32, 64, 1), 256, 0, stream>>>(tp, D_HID, D_IN);
    }

    // 10. fused h_t + GroupNorm + skip + silu-gate -> tmp_bf (and ht to d_out)
    hgnorm_kernel<<<B_ROWS * NH, 128, 0, stream>>>(
        opb_bf, ct, qb, denom, gn_w, gn_b, xskip_bf, xupR_bf, ht, tmp_bf);

    // 11. down-projection + residual -> final (R4-proven mgemm<64,4>, grid 256)
    mgemm<64, 4><<<dim3(16, 16, 1), 256, 0, stream>>>(
        tmp_bf, dwT, down_b, x, final_o, nullptr, D_HID, D_HID, D_HID, D_IN);
}

// Round 22
// 556.144 us; speedup vs baseline: 1.1804x; 1.1804x over previous
//
#include <hip/hip_runtime.h>
#include <math.h>

#define B_ROWS 1024
#define D_IN   2048
#define D_HID  4096
#define D_UP   4096
#define NH     8
#define HS     512
#define LN_EPS 1e-5f

typedef __attribute__((ext_vector_type(8))) short bf16x8_t;
typedef __attribute__((ext_vector_type(4))) float f32x4_t;
typedef __attribute__((ext_vector_type(4))) unsigned short us4_t;

__device__ __forceinline__ unsigned short f2bf(float f) {
    unsigned int u = __float_as_uint(f);
    u += 0x7fffu + ((u >> 16) & 1u);
    return (unsigned short)(u >> 16);
}
__device__ __forceinline__ float bf2f(unsigned short u) {
    return __uint_as_float(((unsigned int)u) << 16);
}
__device__ __forceinline__ float sigmoidf_(float x) { return 1.0f / (1.0f + expf(-x)); }
__device__ __forceinline__ float siluf_(float x)    { return x / (1.0f + expf(-x)); }

// global -> LDS direct copy, 16B/lane; lds base wave-uniform, lane l -> base+l*16B.
__device__ __forceinline__ void gload16(const unsigned short* g, unsigned short* l) {
    __builtin_amdgcn_global_load_lds(
        (const __attribute__((address_space(1))) unsigned int*)(const void*)g,
        (__attribute__((address_space(3))) unsigned int*)(void*)l,
        16, 0, 0);
}

#define VMW(n) asm volatile("s_waitcnt vmcnt(" #n ")" ::: "memory")

// XCD-aware swizzle of (bx,by) (R4-proven); requires gx*gy % 8 == 0 (guarded).
#define XCD_SWZ()                                                        \
    int bx = blockIdx.x, by = blockIdx.y;                                \
    {                                                                    \
        const int gx_ = gridDim.x;                                       \
        const int n_  = gx_ * gridDim.y;                                 \
        if ((n_ & 7) == 0) {                                             \
            int lin = by * gx_ + bx;                                     \
            const int q8 = n_ >> 3;                                      \
            lin = (lin & 7) * q8 + (lin >> 3);                           \
            bx = lin % gx_; by = lin / gx_;                              \
        }                                                                \
    }

// ===========================================================================
// mg256: BM=256 x BN=128, 4 waves (2Mx2N), wave tile 128x64. 2 LDS bufs
// (48KB), depth-1 counted-vmcnt prefetch. T21 XOR swizzle (conflict-free,
// R13-proven; R19/R20: 207-210us on step6).
// epi: 0 f32, 2 f32*alpha, 3 abs-row-max->denom, 5 bf16.
// ===========================================================================
struct MGChunk {
    const unsigned short* A;
    const unsigned short* Bt;
    const float* bias;
    const float* resid;
    float* C;
    unsigned short* C2;
    float* denom;
    float alpha;
    int epi;
};

template<int NCH>
__global__ __launch_bounds__(256, 3) void mg256(
    MGChunk c0, MGChunk c1, MGChunk c2, MGChunk c3,
    int K, int lda, int ldbt, int ldc, int bpc,
    long aB, long wB, long bB, long cB)
{
    const int gx = gridDim.x, gy = gridDim.y;
    const int n = gx * gy;
    const int orig = blockIdx.y * gx + blockIdx.x;
    const int wl = ((n & 7) == 0) ? ((orig & 7) * (n >> 3) + (orig >> 3)) : orig;
    const int bxw = wl / gy;
    const int byw = wl - bxw * gy;
    const int chid = (NCH > 1) ? (bxw / bpc) : 0;
    const int cbx = bxw - chid * bpc;
    const MGChunk ch = (chid == 0) ? c0 : ((chid == 1) ? c1 : ((chid == 2) ? c2 : c3));
    const int bz = blockIdx.z;

    const unsigned short* A  = ch.A  + bz * aB;
    const unsigned short* Bt = ch.Bt + bz * wB;

    __shared__ __align__(16) unsigned short As[2][256][32];
    __shared__ __align__(16) unsigned short Bs[2][128][32];

    const int t = threadIdx.x;
    const int w = t >> 6, l = t & 63;
    const int wrm = w >> 1;
    const int wcn = w & 1;
    const long rowA = (long)byw * 256;
    const long rowB = (long)cbx * 128;

    const int skz = (((l & 3) ^ ((l >> 3) & 3)) << 3);
    const unsigned short* Ag = A  + rowA * (long)lda;
    const unsigned short* Bg = Bt + rowB * (long)ldbt;

    const int lm  = l & 15;
    const int pkz = (((l >> 4) ^ ((l >> 1) & 3)) << 3);

    f32x4_t acc[8][4];
#pragma unroll
    for (int mi = 0; mi < 8; ++mi)
#pragma unroll
        for (int ni = 0; ni < 4; ++ni) acc[mi][ni] = (f32x4_t)0.0f;

#define STAGE(buf, kb)                                                        \
    {                                                                         \
        _Pragma("unroll")                                                     \
        for (int p = 0; p < 4; ++p)                                           \
            gload16(Ag + (long)(w * 64 + p * 16 + (l >> 2)) * lda + (kb) + skz, \
                    &As[buf][w * 64 + p * 16][0]);                            \
        _Pragma("unroll")                                                     \
        for (int p = 0; p < 2; ++p)                                           \
            gload16(Bg + (long)(w * 32 + p * 16 + (l >> 2)) * ldbt + (kb) + skz, \
                    &Bs[buf][w * 32 + p * 16][0]);                            \
    }

    const int nsteps = K >> 5;
    STAGE(0, 0);

    int cur = 0;
    for (int ti = 0; ti < nsteps; ++ti) {
        if (ti + 1 < nsteps) {
            STAGE(cur ^ 1, (ti + 1) << 5);
            VMW(6);                        // drains buf[cur]'s 6 loads
        } else {
            VMW(0);
        }
        __builtin_amdgcn_s_barrier();      // buf[cur] visible block-wide

        bf16x8_t bfr[4];
#pragma unroll
        for (int ni = 0; ni < 4; ++ni)
            bfr[ni] = *(const bf16x8_t*)&Bs[cur][wcn * 64 + ni * 16 + lm][pkz];
#pragma unroll
        for (int mi = 0; mi < 8; ++mi) {
            const bf16x8_t af = *(const bf16x8_t*)&As[cur][wrm * 128 + mi * 16 + lm][pkz];
#pragma unroll
            for (int ni = 0; ni < 4; ++ni)
                acc[mi][ni] = __builtin_amdgcn_mfma_f32_16x16x32_bf16(
                    af, bfr[ni], acc[mi][ni], 0, 0, 0);
        }

        asm volatile("s_waitcnt lgkmcnt(0)" ::: "memory");
        __builtin_amdgcn_s_barrier();      // reads of buf[cur] done
        cur ^= 1;
    }
#undef STAGE

    // C/D layout: col = lane&15, row = (lane>>4)*4 + reg
    const int lr4 = (l >> 4) * 4;
    if (ch.epi == 3) {
        float rmax[8][4];
#pragma unroll
        for (int mi = 0; mi < 8; ++mi)
#pragma unroll
            for (int r = 0; r < 4; ++r) {
                float m = 0.0f;
#pragma unroll
                for (int ni = 0; ni < 4; ++ni) m = fmaxf(m, fabsf(acc[mi][ni][r]));
                rmax[mi][r] = m;
            }
#pragma unroll
        for (int off = 1; off < 16; off <<= 1)
#pragma unroll
            for (int mi = 0; mi < 8; ++mi)
#pragma unroll
                for (int r = 0; r < 4; ++r)
                    rmax[mi][r] = fmaxf(rmax[mi][r], __shfl_xor(rmax[mi][r], off, 64));
        if (lm == 0) {
#pragma unroll
            for (int mi = 0; mi < 8; ++mi)
#pragma unroll
                for (int r = 0; r < 4; ++r) {
                    const long m = rowA + wrm * 128 + mi * 16 + lr4 + r;
                    atomicMax((unsigned int*)&ch.denom[m], __float_as_uint(rmax[mi][r]));
                }
        }
        return;
    }
    const float* bias = ch.bias + bz * bB;
#pragma unroll
    for (int mi = 0; mi < 8; ++mi) {
        const long m0 = rowA + wrm * 128 + mi * 16 + lr4;
#pragma unroll
        for (int ni = 0; ni < 4; ++ni) {
            const long nn = rowB + wcn * 64 + ni * 16 + lm;
            const float bv = bias[nn];
#pragma unroll
            for (int r = 0; r < 4; ++r) {
                float v = acc[mi][ni][r] + bv;
                if (ch.epi == 2) v *= ch.alpha;
                const long m = m0 + r;
                if (ch.epi == 5) (ch.C2 + bz * cB)[m * ldc + nn] = f2bf(v);
                else             (ch.C  + bz * cB)[m * ldc + nn] = v;
            }
        }
    }
}

// ===========================================================================
// mgemm_mc: R4-proven reg-staged double-buffered 128x128 multi-chunk GEMM
// (padded 40-el LDS rows). epi: 0 = f32 out (alpha*(acc+bias)); 5 = bf16 out.
// ===========================================================================
struct MCChunk {
    const unsigned short* A;
    const unsigned short* Bt;
    const float* bias;
    float* C;
    unsigned short* C2;
    float alpha;
    int epi;
};

template<int NCH>
__global__ __launch_bounds__(256) void mgemm_mc(
    MCChunk c0, MCChunk c1, MCChunk c2,
    int K, int lda, int ldbt, int ldc, int bpc,
    long aB, long wB, long bB, long cB)
{
    XCD_SWZ();
    const int chid = bx / bpc;
    const int cbx  = bx - chid * bpc;
    const MCChunk ch = (chid == 0) ? c0 : ((NCH > 1 && chid == 1) ? c1 : c2);
    const int bz = blockIdx.z;

    const unsigned short* A  = ch.A  + bz * aB;
    const unsigned short* Bt = ch.Bt + bz * wB;
    const float* bias = ch.bias + bz * bB;

    __shared__ __align__(16) unsigned short As[2][128][40];
    __shared__ __align__(16) unsigned short Bs[2][128][40];

    const int t = threadIdx.x;
    const int w = t >> 6, l = t & 63;
    const int wr = w >> 1, wc = w & 1;
    const long rowA = (long)by * 128;
    const long rowB = (long)cbx * 128;

    const int lr = t >> 2;
    const int lc = (t & 3) << 3;
    const unsigned short* Ag = A  + (rowA + lr) * (long)lda  + lc;
    const unsigned short* Bg = Bt + (rowB + lr) * (long)ldbt + lc;

    const int lm = l & 15;
    const int lk = (l >> 4) * 8;

    f32x4_t acc[4][4];
#pragma unroll
    for (int mi = 0; mi < 4; ++mi)
#pragma unroll
        for (int ni = 0; ni < 4; ++ni) acc[mi][ni] = (f32x4_t)0.0f;

    bf16x8_t ra[2], rb[2];
#pragma unroll
    for (int p = 0; p < 2; ++p) {
        ra[p] = *(const bf16x8_t*)(Ag + (long)p * 64 * lda);
        rb[p] = *(const bf16x8_t*)(Bg + (long)p * 64 * ldbt);
    }
#pragma unroll
    for (int p = 0; p < 2; ++p) {
        *(bf16x8_t*)&As[0][lr + p * 64][lc] = ra[p];
        *(bf16x8_t*)&Bs[0][lr + p * 64][lc] = rb[p];
    }
    __syncthreads();

    const int nsteps = K >> 5;
    for (int ti = 0; ti < nsteps; ++ti) {
        const int cur = ti & 1;
        if (ti + 1 < nsteps) {
            const int kb = (ti + 1) << 5;
#pragma unroll
            for (int p = 0; p < 2; ++p) {
                ra[p] = *(const bf16x8_t*)(Ag + (long)p * 64 * lda  + kb);
                rb[p] = *(const bf16x8_t*)(Bg + (long)p * 64 * ldbt + kb);
            }
        }
        bf16x8_t af[4], bfr[4];
#pragma unroll
        for (int mi = 0; mi < 4; ++mi)
            af[mi] = *(const bf16x8_t*)&As[cur][wr * 64 + mi * 16 + lm][lk];
#pragma unroll
        for (int ni = 0; ni < 4; ++ni)
            bfr[ni] = *(const bf16x8_t*)&Bs[cur][wc * 64 + ni * 16 + lm][lk];
#pragma unroll
        for (int mi = 0; mi < 4; ++mi)
#pragma unroll
            for (int ni = 0; ni < 4; ++ni)
                acc[mi][ni] = __builtin_amdgcn_mfma_f32_16x16x32_bf16(
                    af[mi], bfr[ni], acc[mi][ni], 0, 0, 0);
        if (ti + 1 < nsteps) {
            const int nxt = cur ^ 1;
#pragma unroll
            for (int p = 0; p < 2; ++p) {
                *(bf16x8_t*)&As[nxt][lr + p * 64][lc] = ra[p];
                *(bf16x8_t*)&Bs[nxt][lr + p * 64][lc] = rb[p];
            }
        }
        __syncthreads();
    }

    const int lr4 = (l >> 4) * 4;
    const float alpha = ch.alpha;
#pragma unroll
    for (int mi = 0; mi < 4; ++mi) {
        const long m0 = rowA + wr * 64 + mi * 16 + lr4;
#pragma unroll
        for (int ni = 0; ni < 4; ++ni) {
            const long nn = rowB + wc * 64 + ni * 16 + lm;
            const float bv = bias[nn];
#pragma unroll
            for (int r = 0; r < 4; ++r) {
                const float v = (acc[mi][ni][r] + bv) * alpha;
                const long m = m0 + r;
                if (ch.epi == 5) (ch.C2 + bz * cB)[m * ldc + nn] = f2bf(v);
                else             (ch.C  + bz * cB)[m * ldc + nn] = v;
            }
        }
    }
}

// ===========================================================================
// mgemm: R4-proven single-chunk reg-staged GEMM. EPI 4 = f32 acc+bias+resid.
// ===========================================================================
template<int BM, int EPI>
__global__ __launch_bounds__(256) void mgemm(
    const unsigned short* __restrict__ A, const unsigned short* __restrict__ Bt,
    const float* __restrict__ bias, const float* __restrict__ resid,
    float* __restrict__ C, float* __restrict__ denom,
    int K, int lda, int ldbt, int ldc)
{
    constexpr int MR = BM / 32;
    constexpr int AP = BM / 64;
    XCD_SWZ();

    __shared__ __align__(16) unsigned short As[2][BM][40];
    __shared__ __align__(16) unsigned short Bs[2][128][40];

    const int t = threadIdx.x;
    const int w = t >> 6, l = t & 63;
    const int wr = w >> 1, wc = w & 1;
    const long rowA = (long)by * BM;
    const long rowB = (long)bx * 128;

    const int lr = t >> 2;
    const int lc = (t & 3) << 3;
    const unsigned short* Ag = A  + (rowA + lr) * (long)lda  + lc;
    const unsigned short* Bg = Bt + (rowB + lr) * (long)ldbt + lc;

    const int lm = l & 15;
    const int lk = (l >> 4) * 8;

    f32x4_t acc[MR][4];
#pragma unroll
    for (int mi = 0; mi < MR; ++mi)
#pragma unroll
        for (int ni = 0; ni < 4; ++ni) acc[mi][ni] = (f32x4_t)0.0f;

    bf16x8_t ra[AP], rb[2];
#pragma unroll
    for (int p = 0; p < AP; ++p) ra[p] = *(const bf16x8_t*)(Ag + (long)p * 64 * lda);
#pragma unroll
    for (int p = 0; p < 2;  ++p) rb[p] = *(const bf16x8_t*)(Bg + (long)p * 64 * ldbt);
#pragma unroll
    for (int p = 0; p < AP; ++p) *(bf16x8_t*)&As[0][lr + p * 64][lc] = ra[p];
#pragma unroll
    for (int p = 0; p < 2;  ++p) *(bf16x8_t*)&Bs[0][lr + p * 64][lc] = rb[p];
    __syncthreads();

    const int nsteps = K >> 5;
    for (int ti = 0; ti < nsteps; ++ti) {
        const int cur = ti & 1;
        if (ti + 1 < nsteps) {
            const int kb = (ti + 1) << 5;
#pragma unroll
            for (int p = 0; p < AP; ++p) ra[p] = *(const bf16x8_t*)(Ag + (long)p * 64 * lda  + kb);
#pragma unroll
            for (int p = 0; p < 2;  ++p) rb[p] = *(const bf16x8_t*)(Bg + (long)p * 64 * ldbt + kb);
        }
        bf16x8_t af[MR], bfr[4];
#pragma unroll
        for (int mi = 0; mi < MR; ++mi)
            af[mi] = *(const bf16x8_t*)&As[cur][wr * (BM / 2) + mi * 16 + lm][lk];
#pragma unroll
        for (int ni = 0; ni < 4; ++ni)
            bfr[ni] = *(const bf16x8_t*)&Bs[cur][wc * 64 + ni * 16 + lm][lk];
#pragma unroll
        for (int mi = 0; mi < MR; ++mi)
#pragma unroll
            for (int ni = 0; ni < 4; ++ni)
                acc[mi][ni] = __builtin_amdgcn_mfma_f32_16x16x32_bf16(
                    af[mi], bfr[ni], acc[mi][ni], 0, 0, 0);
        if (ti + 1 < nsteps) {
            const int nxt = cur ^ 1;
#pragma unroll
            for (int p = 0; p < AP; ++p) *(bf16x8_t*)&As[nxt][lr + p * 64][lc] = ra[p];
#pragma unroll
            for (int p = 0; p < 2;  ++p) *(bf16x8_t*)&Bs[nxt][lr + p * 64][lc] = rb[p];
        }
        __syncthreads();
    }

    const int lr4 = (l >> 4) * 4;
#pragma unroll
    for (int mi = 0; mi < MR; ++mi) {
        const long m0 = rowA + wr * (BM / 2) + mi * 16 + lr4;
#pragma unroll
        for (int ni = 0; ni < 4; ++ni) {
            const long nn = rowB + wc * 64 + ni * 16 + lm;
            const float bv = bias[nn];
#pragma unroll
            for (int r = 0; r < 4; ++r) {
                float v = acc[mi][ni][r] + bv;
                const long m = m0 + r;
                if (EPI == 4) v += resid[m * ldc + nn];
                C[m * ldc + nn] = v;
            }
        }
    }
}

// ---------------------------------------------------------------------------
// Batched transpose + f32->bf16: src (R,C) f32 -> dst (C,R) bf16, z-indexed.
// 16B/lane stores (bf16x8). R18-proven.
// ---------------------------------------------------------------------------
struct TP4 {
    const float* s0; const float* s1; const float* s2; const float* s3;
    unsigned short* d0; unsigned short* d1; unsigned short* d2; unsigned short* d3;
};

__global__ __launch_bounds__(256) void tp_batch(TP4 tp, int R, int C)
{
    const int z = blockIdx.z;
    const float* X = (z == 0) ? tp.s0 : (z == 1) ? tp.s1 : (z == 2) ? tp.s2 : tp.s3;
    unsigned short* XT = (z == 0) ? tp.d0 : (z == 1) ? tp.d1 : (z == 2) ? tp.d2 : tp.d3;
    __shared__ float tile[64][65];
    const int t = threadIdx.x;
    const long r0 = (long)blockIdx.y * 64;
    const long c0 = (long)blockIdx.x * 64;
    const int tr = t >> 4;
    const int tc = (t & 15) << 2;
#pragma unroll
    for (int p = 0; p < 4; ++p) {
        const float4 v = *(const float4*)(X + (r0 + tr + p * 16) * C + c0 + tc);
        tile[tr + p * 16][tc + 0] = v.x;
        tile[tr + p * 16][tc + 1] = v.y;
        tile[tr + p * 16][tc + 2] = v.z;
        tile[tr + p * 16][tc + 3] = v.w;
    }
    __syncthreads();
#pragma unroll
    for (int p = 0; p < 2; ++p) {
        const int orow = (t >> 3) + p * 32;
        const int oc8  = (t & 7) * 8;
        unsigned short tmp[8];
#pragma unroll
        for (int j = 0; j < 8; ++j) tmp[j] = f2bf(tile[oc8 + j][orow]);
        *(bf16x8_t*)(XT + (c0 + orow) * (long)R + r0 + oc8) = *(const bf16x8_t*)tmp;
    }
}

// qkv weights: (NH,HS,HS) f32 x3 -> concatenated (3,NH,HS,HS) bf16 transposed
__global__ __launch_bounds__(256) void tp_qkv(
    const float* wq, const float* wk, const float* wv, unsigned short* dst)
{
    const int z = blockIdx.z;
    const int sel = z >> 3, head = z & 7;
    const float* X = ((sel == 0) ? wq : (sel == 1) ? wk : wv) + (long)head * HS * HS;
    unsigned short* XT = dst + (long)sel * NH * HS * HS + (long)head * HS * HS;
    __shared__ float tile[64][65];
    const int t = threadIdx.x;
    const long r0 = (long)blockIdx.y * 64;
    const long c0 = (long)blockIdx.x * 64;
    const int tr = t >> 4;
    const int tc = (t & 15) << 2;
#pragma unroll
    for (int p = 0; p < 4; ++p) {
        const float4 v = *(const float4*)(X + (r0 + tr + p * 16) * HS + c0 + tc);
        tile[tr + p * 16][tc + 0] = v.x;
        tile[tr + p * 16][tc + 1] = v.y;
        tile[tr + p * 16][tc + 2] = v.z;
        tile[tr + p * 16][tc + 3] = v.w;
    }
    __syncthreads();
#pragma unroll
    for (int p = 0; p < 2; ++p) {
        const int orow = (t >> 3) + p * 32;
        const int oc8  = (t & 7) * 8;
        unsigned short tmp[8];
#pragma unroll
        for (int j = 0; j < 8; ++j) tmp[j] = f2bf(tile[oc8 + j][orow]);
        *(bf16x8_t*)(XT + (c0 + orow) * (long)HS + r0 + oc8) = *(const bf16x8_t*)tmp;
    }
}

// ---------------------------------------------------------------------------
// LayerNorm over D_IN per row -> bf16
// ---------------------------------------------------------------------------
__global__ __launch_bounds__(256) void layernorm_kernel(
    const float* __restrict__ x, const float* __restrict__ w,
    const float* __restrict__ b, unsigned short* __restrict__ out)
{
    __shared__ float sh[8];
    const int row = blockIdx.x, t = threadIdx.x;
    const float* xr = x + (long)row * D_IN;
    float v[8];
    float s = 0.f, ss = 0.f;
#pragma unroll
    for (int i = 0; i < 8; ++i) {
        v[i] = xr[t + 256 * i];
        s += v[i];
        ss += v[i] * v[i];
    }
#pragma unroll
    for (int off = 32; off; off >>= 1) {
        s  += __shfl_down(s, off, 64);
        ss += __shfl_down(ss, off, 64);
    }
    const int lane = t & 63, wid = t >> 6;
    if (lane == 0) { sh[wid * 2] = s; sh[wid * 2 + 1] = ss; }
    __syncthreads();
    s = 0.f; ss = 0.f;
#pragma unroll
    for (int i = 0; i < 4; ++i) { s += sh[i * 2]; ss += sh[i * 2 + 1]; }
    const float mu  = s * (1.0f / D_IN);
    const float var = ss * (1.0f / D_IN) - mu * mu;
    const float rs  = rsqrtf(var + LN_EPS);
    unsigned short* orow = out + (long)row * D_IN;
#pragma unroll
    for (int i = 0; i < 8; ++i) {
        const int d = t + 256 * i;
        orow[d] = f2bf((v[i] - mu) * rs * w[d] + b[d]);
    }
}

// ---------------------------------------------------------------------------
// Causal conv1d (K=4, left pad 3) + SiLU.  bf16 -> bf16
// ---------------------------------------------------------------------------
__global__ void conv_silu_kernel(const unsigned short* __restrict__ xl,
                                 const float* __restrict__ cw,
                                 const float* __restrict__ cb,
                                 unsigned short* __restrict__ out)
{
    const long idx = (long)blockIdx.x * blockDim.x + threadIdx.x;
    if (idx >= (long)B_ROWS * D_UP) return;
    const int d = (int)(idx & (D_UP - 1));
    const float w0 = cw[0], w1 = cw[1], w2 = cw[2], w3 = cw[3];
    float acc = cb[0] + w3 * bf2f(xl[idx]);
    if (d >= 1) acc += w2 * bf2f(xl[idx - 1]);
    if (d >= 2) acc += w1 * bf2f(xl[idx - 2]);
    if (d >= 3) acc += w0 * bf2f(xl[idx - 3]);
    out[idx] = f2bf(siluf_(acc));
}

// ---------------------------------------------------------------------------
// Stabilized exponential gating, float4-vectorized -> m_t, c_t, n_t
// ---------------------------------------------------------------------------
__global__ void gating_kernel(const float4* __restrict__ it, const float4* __restrict__ ft,
                              const float4* __restrict__ mp, const float4* __restrict__ cp,
                              const float4* __restrict__ np_, const float4* __restrict__ kk,
                              const float4* __restrict__ vv,
                              float4* __restrict__ mt, float4* __restrict__ ct,
                              float4* __restrict__ nt)
{
    const long idx = (long)blockIdx.x * blockDim.x + threadIdx.x;
    if (idx >= (long)B_ROWS * D_HID / 4) return;
    const float4 i4 = it[idx], f4 = ft[idx], mp4 = mp[idx];
    const float4 cp4 = cp[idx], np4 = np_[idx], k4 = kk[idx], v4 = vv[idx];
    float4 m4, c4, n4;
#pragma unroll
    for (int j = 0; j < 4; ++j) {
        const float i_t = (&i4.x)[j];
        const float f_t = (&f4.x)[j] + (&mp4.x)[j];
        const float m_t = fmaxf(f_t, i_t);
        const float i_g = expf(i_t - m_t);
        const float f_g = expf(f_t - m_t);
        const float kv  = (&k4.x)[j];
        (&c4.x)[j] = f_g * (&cp4.x)[j] + i_g * ((&v4.x)[j] * kv);
        (&n4.x)[j] = f_g * (&np4.x)[j] + i_g * kv;
        (&m4.x)[j] = m_t;
    }
    ct[idx] = c4;
    nt[idx] = n4;
    mt[idx] = m4;
}

// ---------------------------------------------------------------------------
// Fused: h_t = sigmoid(op)*c_t*q/denom  +  GroupNorm + skip + silu-gate
// ---------------------------------------------------------------------------
__global__ __launch_bounds__(128) void hgnorm_kernel(
    const unsigned short* __restrict__ op, const float* __restrict__ ct,
    const float* __restrict__ qb, const float* __restrict__ denom,
    const float* __restrict__ gw, const float* __restrict__ gb,
    const unsigned short* __restrict__ xskip, const unsigned short* __restrict__ xupR,
    float* __restrict__ ht, unsigned short* __restrict__ out)
{
    __shared__ float sh[4];
    const int b = blockIdx.x >> 3, h = blockIdx.x & 7;
    const int t = threadIdx.x;
    const long base = (long)b * D_HID + h * HS;
    float v[4];
    float s = 0.f, ss = 0.f;
#pragma unroll
    for (int i = 0; i < 4; ++i) {
        const long ix = base + t + 128 * i;
        const int  dg = h * HS + t + 128 * i;
        const float hv = sigmoidf_(bf2f(op[ix])) * ct[ix] * qb[ix] / denom[dg];
        ht[ix] = hv;
        v[i] = hv;
        s += hv;
        ss += hv * hv;
    }
#pragma unroll
    for (int off = 32; off; off >>= 1) {
        s  += __shfl_down(s, off, 64);
        ss += __shfl_down(ss, off, 64);
    }
    if ((t & 63) == 0) { sh[(t >> 6) * 2] = s; sh[(t >> 6) * 2 + 1] = ss; }
    __syncthreads();
    s = sh[0] + sh[2];
    ss = sh[1] + sh[3];
    const float mu  = s * (1.0f / HS);
    const float var = ss * (1.0f / HS) - mu * mu;
    const float rs  = rsqrtf(var + LN_EPS);
#pragma unroll
    for (int i = 0; i < 4; ++i) {
        const int  dg = h * HS + t + 128 * i;
        const long ix = base + t + 128 * i;
        const float g = (v[i] - mu) * rs * gw[dg] + gb[dg];
        out[ix] = f2bf((g + bf2f(xskip[ix])) * siluf_(bf2f(xupR[ix])));
    }
}

// ---------------------------------------------------------------------------
extern "C" void kernel_launch(void* const* d_in, const int* in_sizes, int n_in,
                              void* d_out, int out_size, void* d_ws, size_t ws_size,
                              hipStream_t stream)
{
    const float* x      = (const float*)d_in[0];
    const float* c_prev = (const float*)d_in[2];
    const float* n_prev = (const float*)d_in[3];
    const float* m_prev = (const float*)d_in[4];
    const float* ln_w   = (const float*)d_in[5];
    const float* ln_b   = (const float*)d_in[6];
    const float* upL_w  = (const float*)d_in[7];
    const float* upL_b  = (const float*)d_in[8];
    const float* upR_w  = (const float*)d_in[9];
    const float* upR_b  = (const float*)d_in[10];
    const float* conv_w = (const float*)d_in[11];
    const float* conv_b = (const float*)d_in[12];
    const float* skip_w = (const float*)d_in[13];
    const float* skip_b = (const float*)d_in[14];
    const float* wq     = (const float*)d_in[15];
    const float* bq     = (const float*)d_in[16];
    const float* wk     = (const float*)d_in[17];
    const float* bk     = (const float*)d_in[18];
    const float* wv     = (const float*)d_in[19];
    const float* bv     = (const float*)d_in[20];
    const float* wi_w   = (const float*)d_in[21];
    const float* wi_b   = (const float*)d_in[22];
    const float* wf_w   = (const float*)d_in[23];
    const float* wf_b   = (const float*)d_in[24];
    const float* wo_w   = (const float*)d_in[25];
    const float* wo_b   = (const float*)d_in[26];
    const float* gn_w   = (const float*)d_in[27];
    const float* gn_b   = (const float*)d_in[28];
    const float* down_w = (const float*)d_in[29];
    const float* down_b = (const float*)d_in[30];

    float* out     = (float*)d_out;
    float* final_o = out;                       // (1024, 2048)  [0, 2M) f32
    float* ht      = final_o + 2097152;         // [2M, 6M)
    float* ct      = ht + 4194304;              // [6M, 10M)
    float* nt      = ct + 4194304;              // [10M, 14M)
    float* mt      = nt + 4194304;              // [14M, 18M)

    // d_out scratch: WTA = ht+ct, WTB = nt+mt; consumed before gating/hgnorm
    // write those regions (stream-serial).
    unsigned short* WTA = (unsigned short*)ht;
    unsigned short* WTB = (unsigned short*)nt;

    // ---- workspace layout (float units; M = 1M floats). Peak ≈ 162MB.
    const long M = 1048576;
    float* ws = (float*)d_ws;
    float* qb  = ws +  0 * M;                                  // [0,4M)   step7..11
    float* kb  = ws +  4 * M;                                  // [4,8M)   step7..8
    float* vb  = ws +  8 * M;                                  // [8,12M)  step7..8
    float* itb = ws + 12 * M;                                  // [12,16M) step6..8
    float* ftb = ws + 16 * M;                                  // [16,20M) step6..8
    unsigned short* xupR_bf  = (unsigned short*)(ws + 20 * M); // step3..11
    unsigned short* xskip_bf = (unsigned short*)(ws + 22 * M); // step6..11
    unsigned short* opb_bf   = (unsigned short*)(ws + 24 * M); // step6..11
    unsigned short* xnorm_bf = (unsigned short*)(ws + 26 * M); // step1..3
    unsigned short* xupL_bf  = (unsigned short*)(ws + 27 * M); // step3..7
    unsigned short* xconv_bf = (unsigned short*)(ws + 29 * M); // step4..7
    float* denom             = ws + 31 * M;                    // 4096 f32
    unsigned short* WTC      = (unsigned short*)(ws + 32 * M); // wf^T, step5..6
    unsigned short* WTD      = (unsigned short*)(ws +  0 * M); // wo^T, step5..6 (dead before qb/kb)
    unsigned short* ntT      = (unsigned short*)(ws + 26 * M); // step9 (xnorm/xupL dead)
    unsigned short* qT       = (unsigned short*)(ws + 28 * M); // step9 (xupL/xconv dead)
    unsigned short* dwT      = (unsigned short*)(ws + 12 * M); // down^T, step10..12
    unsigned short* tmp_bf   = (unsigned short*)(ws +  8 * M); // step11..12 (vb dead)

    const float kscale = 1.0f / sqrtf((float)HS);
    const long HS2 = (long)HS * HS;
    MGChunk cz = {};
    MCChunk mz = {};

    // 1. LayerNorm -> bf16
    layernorm_kernel<<<B_ROWS, 256, 0, stream>>>(x, ln_w, ln_b, xnorm_bf);

    // 2. upL^T, upR^T -> WTA
    {
        TP4 tp = { upL_w, upR_w, nullptr, nullptr, WTA, WTA + 8388608, nullptr, nullptr };
        tp_batch<<<dim3(64, 32, 2), 256, 0, stream>>>(tp, D_IN, D_UP);
    }
    // 3. upL | upR GEMM (R4-proven mgemm_mc, grid 512)
    {
        MCChunk a = { xnorm_bf, WTA,           upL_b, nullptr, xupL_bf, 1.0f, 5 };
        MCChunk b = { xnorm_bf, WTA + 8388608, upR_b, nullptr, xupR_bf, 1.0f, 5 };
        mgemm_mc<2><<<dim3(64, 8, 1), 256, 0, stream>>>(
            a, b, mz, D_IN, D_IN, D_IN, D_HID, 32, 0, 0, 0, 0);
    }

    // 4. causal conv + silu -> bf16
    conv_silu_kernel<<<(B_ROWS * D_UP) / 256, 256, 0, stream>>>(xupL_bf, conv_w, conv_b, xconv_bf);

    // 5. skip^T->WTA, wi^T->WTB, wf^T->WTC, wo^T->WTD
    {
        TP4 tp = { skip_w, wi_w, wf_w, wo_w, WTA, WTB, WTC, WTD };
        tp_batch<<<dim3(64, 64, 4), 256, 0, stream>>>(tp, D_UP, D_HID);
    }
    // 6. skip | wi | wf | wo in ONE mg256 dispatch (grid 512)
    {
        MGChunk a = { xconv_bf, WTA, skip_b, nullptr, nullptr, xskip_bf, nullptr, 1.0f, 5 };
        MGChunk b = { xconv_bf, WTB, wi_b,   nullptr, itb,     nullptr,  nullptr, 1.0f, 0 };
        MGChunk c = { xconv_bf, WTC, wf_b,   nullptr, ftb,     nullptr,  nullptr, 1.0f, 0 };
        MGChunk d = { xupL_bf,  WTD, wo_b,   nullptr, nullptr, opb_bf,   nullptr, 1.0f, 5 };
        mg256<4><<<dim3(128, 4, 1), 256, 0, stream>>>(
            a, b, c, d, D_UP, D_UP, D_UP, D_HID, 32, 0, 0, 0, 0);
    }

    // 7. qkv^T -> WTA, then q | k | v head-batched (R4-proven mgemm_mc, grid 768)
    tp_qkv<<<dim3(8, 8, 24), 256, 0, stream>>>(wq, wk, wv, WTA);
    {
        MCChunk a = { xconv_bf, WTA,                bq, qb, nullptr, 1.0f,   0 };
        MCChunk b = { xconv_bf, WTA + NH * HS2,     bk, kb, nullptr, kscale, 0 };
        MCChunk c = { xupL_bf,  WTA + 2 * NH * HS2, bv, vb, nullptr, 1.0f,   0 };
        mgemm_mc<3><<<dim3(12, 8, NH), 256, 0, stream>>>(
            a, b, c, HS, D_UP, HS, D_HID, 4, HS, HS2, HS, HS);
    }

    // 8. gating (float4) -> m_t, c_t, n_t
    gating_kernel<<<(B_ROWS * D_HID / 4) / 256, 256, 0, stream>>>(
        (const float4*)itb, (const float4*)ftb, (const float4*)m_prev,
        (const float4*)c_prev, (const float4*)n_prev, (const float4*)kb,
        (const float4*)vb, (float4*)mt, (float4*)ct, (float4*)nt);

    // 9. nt^T, q^T -> ntT/qT; denom = rowwise max |n_t^T q| via mg256 epi3
    {
        TP4 tp = { nt, qb, nullptr, nullptr, ntT, qT, nullptr, nullptr };
        tp_batch<<<dim3(64, 16, 2), 256, 0, stream>>>(tp, B_ROWS, D_HID);
    }
    hipMemsetAsync(denom, 0, D_HID * sizeof(float), stream);
    {
        MGChunk a = { ntT, qT, nullptr, nullptr, nullptr, nullptr, denom, 1.0f, 3 };
        mg256<1><<<dim3(32, 16, 1), 256, 0, stream>>>(
            a, cz, cz, cz, B_ROWS, B_ROWS, B_ROWS, 0, 32, 0, 0, 0, 0);
    }

    // 10. down^T -> dwT
    {
        TP4 tp = { down_w, nullptr, nullptr, nullptr, dwT, nullptr, nullptr, nullptr };
        tp_batch<<<dim3(32, 64, 1), 256, 0, stream>>>(tp, D_HID, D_IN);
    }

    // 11. fused h_t + GroupNorm + skip + silu-gate -> tmp_bf (and ht to d_out)
    hgnorm_kernel<<<B_ROWS * NH, 128, 0, stream>>>(
        opb_bf, ct, qb, denom, gn_w, gn_b, xskip_bf, xupR_bf, ht, tmp_bf);

    // 12. down-projection + residual -> final (R4-proven mgemm<64,4>, grid 256)
    mgemm<64, 4><<<dim3(16, 16, 1), 256, 0, stream>>>(
        tmp_bf, dwT, down_b, x, final_o, nullptr, D_HID, D_HID, D_HID, D_IN);
}

// Round 23
// 554.320 us; speedup vs baseline: 1.1843x; 1.0033x over previous
//
#include <hip/hip_runtime.h>
#include <math.h>

#define B_ROWS 1024
#define D_IN   2048
#define D_HID  4096
#define D_UP   4096
#define NH     8
#define HS     512
#define LN_EPS 1e-5f

typedef __attribute__((ext_vector_type(8))) short bf16x8_t;
typedef __attribute__((ext_vector_type(4))) float f32x4_t;
typedef __attribute__((ext_vector_type(4))) unsigned short us4_t;

__device__ __forceinline__ unsigned short f2bf(float f) {
    unsigned int u = __float_as_uint(f);
    u += 0x7fffu + ((u >> 16) & 1u);
    return (unsigned short)(u >> 16);
}
__device__ __forceinline__ float bf2f(unsigned short u) {
    return __uint_as_float(((unsigned int)u) << 16);
}
__device__ __forceinline__ float sigmoidf_(float x) { return 1.0f / (1.0f + expf(-x)); }
__device__ __forceinline__ float siluf_(float x)    { return x / (1.0f + expf(-x)); }

// global -> LDS direct copy, 16B/lane; lds base wave-uniform, lane l -> base+l*16B.
__device__ __forceinline__ void gload16(const unsigned short* g, unsigned short* l) {
    __builtin_amdgcn_global_load_lds(
        (const __attribute__((address_space(1))) unsigned int*)(const void*)g,
        (__attribute__((address_space(3))) unsigned int*)(void*)l,
        16, 0, 0);
}

#define VMW(n) asm volatile("s_waitcnt vmcnt(" #n ")" ::: "memory")

// XCD-aware swizzle of (bx,by) (R4-proven); requires gx*gy % 8 == 0 (guarded).
#define XCD_SWZ()                                                        \
    int bx = blockIdx.x, by = blockIdx.y;                                \
    {                                                                    \
        const int gx_ = gridDim.x;                                       \
        const int n_  = gx_ * gridDim.y;                                 \
        if ((n_ & 7) == 0) {                                             \
            int lin = by * gx_ + bx;                                     \
            const int q8 = n_ >> 3;                                      \
            lin = (lin & 7) * q8 + (lin >> 3);                           \
            bx = lin % gx_; by = lin / gx_;                              \
        }                                                                \
    }

// ===========================================================================
// mg256: BM=256 x BN=128, 4 waves (2Mx2N), wave tile 128x64. 2 LDS bufs
// (48KB), depth-1 counted-vmcnt prefetch. T21 XOR swizzle (conflict-free,
// R13-proven; R19/R20/R22: 207-210us on step6).
// epi: 0 f32, 2 f32*alpha, 3 abs-row-max->denom, 5 bf16.
// ===========================================================================
struct MGChunk {
    const unsigned short* A;
    const unsigned short* Bt;
    const float* bias;
    const float* resid;
    float* C;
    unsigned short* C2;
    float* denom;
    float alpha;
    int epi;
};

template<int NCH>
__global__ __launch_bounds__(256, 3) void mg256(
    MGChunk c0, MGChunk c1, MGChunk c2, MGChunk c3,
    int K, int lda, int ldbt, int ldc, int bpc,
    long aB, long wB, long bB, long cB)
{
    const int gx = gridDim.x, gy = gridDim.y;
    const int n = gx * gy;
    const int orig = blockIdx.y * gx + blockIdx.x;
    const int wl = ((n & 7) == 0) ? ((orig & 7) * (n >> 3) + (orig >> 3)) : orig;
    const int bxw = wl / gy;
    const int byw = wl - bxw * gy;
    const int chid = (NCH > 1) ? (bxw / bpc) : 0;
    const int cbx = bxw - chid * bpc;
    const MGChunk ch = (chid == 0) ? c0 : ((chid == 1) ? c1 : ((chid == 2) ? c2 : c3));
    const int bz = blockIdx.z;

    const unsigned short* A  = ch.A  + bz * aB;
    const unsigned short* Bt = ch.Bt + bz * wB;

    __shared__ __align__(16) unsigned short As[2][256][32];
    __shared__ __align__(16) unsigned short Bs[2][128][32];

    const int t = threadIdx.x;
    const int w = t >> 6, l = t & 63;
    const int wrm = w >> 1;
    const int wcn = w & 1;
    const long rowA = (long)byw * 256;
    const long rowB = (long)cbx * 128;

    const int skz = (((l & 3) ^ ((l >> 3) & 3)) << 3);
    const unsigned short* Ag = A  + rowA * (long)lda;
    const unsigned short* Bg = Bt + rowB * (long)ldbt;

    const int lm  = l & 15;
    const int pkz = (((l >> 4) ^ ((l >> 1) & 3)) << 3);

    f32x4_t acc[8][4];
#pragma unroll
    for (int mi = 0; mi < 8; ++mi)
#pragma unroll
        for (int ni = 0; ni < 4; ++ni) acc[mi][ni] = (f32x4_t)0.0f;

#define STAGE(buf, kb)                                                        \
    {                                                                         \
        _Pragma("unroll")                                                     \
        for (int p = 0; p < 4; ++p)                                           \
            gload16(Ag + (long)(w * 64 + p * 16 + (l >> 2)) * lda + (kb) + skz, \
                    &As[buf][w * 64 + p * 16][0]);                            \
        _Pragma("unroll")                                                     \
        for (int p = 0; p < 2; ++p)                                           \
            gload16(Bg + (long)(w * 32 + p * 16 + (l >> 2)) * ldbt + (kb) + skz, \
                    &Bs[buf][w * 32 + p * 16][0]);                            \
    }

    const int nsteps = K >> 5;
    STAGE(0, 0);

    int cur = 0;
    for (int ti = 0; ti < nsteps; ++ti) {
        if (ti + 1 < nsteps) {
            STAGE(cur ^ 1, (ti + 1) << 5);
            VMW(6);                        // drains buf[cur]'s 6 loads
        } else {
            VMW(0);
        }
        __builtin_amdgcn_s_barrier();      // buf[cur] visible block-wide

        bf16x8_t bfr[4];
#pragma unroll
        for (int ni = 0; ni < 4; ++ni)
            bfr[ni] = *(const bf16x8_t*)&Bs[cur][wcn * 64 + ni * 16 + lm][pkz];
#pragma unroll
        for (int mi = 0; mi < 8; ++mi) {
            const bf16x8_t af = *(const bf16x8_t*)&As[cur][wrm * 128 + mi * 16 + lm][pkz];
#pragma unroll
            for (int ni = 0; ni < 4; ++ni)
                acc[mi][ni] = __builtin_amdgcn_mfma_f32_16x16x32_bf16(
                    af, bfr[ni], acc[mi][ni], 0, 0, 0);
        }

        asm volatile("s_waitcnt lgkmcnt(0)" ::: "memory");
        __builtin_amdgcn_s_barrier();      // reads of buf[cur] done
        cur ^= 1;
    }
#undef STAGE

    // C/D layout: col = lane&15, row = (lane>>4)*4 + reg
    const int lr4 = (l >> 4) * 4;
    if (ch.epi == 3) {
        float rmax[8][4];
#pragma unroll
        for (int mi = 0; mi < 8; ++mi)
#pragma unroll
            for (int r = 0; r < 4; ++r) {
                float m = 0.0f;
#pragma unroll
                for (int ni = 0; ni < 4; ++ni) m = fmaxf(m, fabsf(acc[mi][ni][r]));
                rmax[mi][r] = m;
            }
#pragma unroll
        for (int off = 1; off < 16; off <<= 1)
#pragma unroll
            for (int mi = 0; mi < 8; ++mi)
#pragma unroll
                for (int r = 0; r < 4; ++r)
                    rmax[mi][r] = fmaxf(rmax[mi][r], __shfl_xor(rmax[mi][r], off, 64));
        if (lm == 0) {
#pragma unroll
            for (int mi = 0; mi < 8; ++mi)
#pragma unroll
                for (int r = 0; r < 4; ++r) {
                    const long m = rowA + wrm * 128 + mi * 16 + lr4 + r;
                    atomicMax((unsigned int*)&ch.denom[m], __float_as_uint(rmax[mi][r]));
                }
        }
        return;
    }
    const float* bias = ch.bias + bz * bB;
#pragma unroll
    for (int mi = 0; mi < 8; ++mi) {
        const long m0 = rowA + wrm * 128 + mi * 16 + lr4;
#pragma unroll
        for (int ni = 0; ni < 4; ++ni) {
            const long nn = rowB + wcn * 64 + ni * 16 + lm;
            const float bv = bias[nn];
#pragma unroll
            for (int r = 0; r < 4; ++r) {
                float v = acc[mi][ni][r] + bv;
                if (ch.epi == 2) v *= ch.alpha;
                const long m = m0 + r;
                if (ch.epi == 5) (ch.C2 + bz * cB)[m * ldc + nn] = f2bf(v);
                else             (ch.C  + bz * cB)[m * ldc + nn] = v;
            }
        }
    }
}

// ===========================================================================
// mgemm_mc: R4-proven reg-staged double-buffered 128x128 multi-chunk GEMM
// (padded 40-el LDS rows). epi: 0 = f32 out (alpha*(acc+bias)); 5 = bf16 out.
// ===========================================================================
struct MCChunk {
    const unsigned short* A;
    const unsigned short* Bt;
    const float* bias;
    float* C;
    unsigned short* C2;
    float alpha;
    int epi;
};

template<int NCH>
__global__ __launch_bounds__(256) void mgemm_mc(
    MCChunk c0, MCChunk c1, MCChunk c2,
    int K, int lda, int ldbt, int ldc, int bpc,
    long aB, long wB, long bB, long cB)
{
    XCD_SWZ();
    const int chid = bx / bpc;
    const int cbx  = bx - chid * bpc;
    const MCChunk ch = (chid == 0) ? c0 : ((NCH > 1 && chid == 1) ? c1 : c2);
    const int bz = blockIdx.z;

    const unsigned short* A  = ch.A  + bz * aB;
    const unsigned short* Bt = ch.Bt + bz * wB;
    const float* bias = ch.bias + bz * bB;

    __shared__ __align__(16) unsigned short As[2][128][40];
    __shared__ __align__(16) unsigned short Bs[2][128][40];

    const int t = threadIdx.x;
    const int w = t >> 6, l = t & 63;
    const int wr = w >> 1, wc = w & 1;
    const long rowA = (long)by * 128;
    const long rowB = (long)cbx * 128;

    const int lr = t >> 2;
    const int lc = (t & 3) << 3;
    const unsigned short* Ag = A  + (rowA + lr) * (long)lda  + lc;
    const unsigned short* Bg = Bt + (rowB + lr) * (long)ldbt + lc;

    const int lm = l & 15;
    const int lk = (l >> 4) * 8;

    f32x4_t acc[4][4];
#pragma unroll
    for (int mi = 0; mi < 4; ++mi)
#pragma unroll
        for (int ni = 0; ni < 4; ++ni) acc[mi][ni] = (f32x4_t)0.0f;

    bf16x8_t ra[2], rb[2];
#pragma unroll
    for (int p = 0; p < 2; ++p) {
        ra[p] = *(const bf16x8_t*)(Ag + (long)p * 64 * lda);
        rb[p] = *(const bf16x8_t*)(Bg + (long)p * 64 * ldbt);
    }
#pragma unroll
    for (int p = 0; p < 2; ++p) {
        *(bf16x8_t*)&As[0][lr + p * 64][lc] = ra[p];
        *(bf16x8_t*)&Bs[0][lr + p * 64][lc] = rb[p];
    }
    __syncthreads();

    const int nsteps = K >> 5;
    for (int ti = 0; ti < nsteps; ++ti) {
        const int cur = ti & 1;
        if (ti + 1 < nsteps) {
            const int kb = (ti + 1) << 5;
#pragma unroll
            for (int p = 0; p < 2; ++p) {
                ra[p] = *(const bf16x8_t*)(Ag + (long)p * 64 * lda  + kb);
                rb[p] = *(const bf16x8_t*)(Bg + (long)p * 64 * ldbt + kb);
            }
        }
        bf16x8_t af[4], bfr[4];
#pragma unroll
        for (int mi = 0; mi < 4; ++mi)
            af[mi] = *(const bf16x8_t*)&As[cur][wr * 64 + mi * 16 + lm][lk];
#pragma unroll
        for (int ni = 0; ni < 4; ++ni)
            bfr[ni] = *(const bf16x8_t*)&Bs[cur][wc * 64 + ni * 16 + lm][lk];
#pragma unroll
        for (int mi = 0; mi < 4; ++mi)
#pragma unroll
            for (int ni = 0; ni < 4; ++ni)
                acc[mi][ni] = __builtin_amdgcn_mfma_f32_16x16x32_bf16(
                    af[mi], bfr[ni], acc[mi][ni], 0, 0, 0);
        if (ti + 1 < nsteps) {
            const int nxt = cur ^ 1;
#pragma unroll
            for (int p = 0; p < 2; ++p) {
                *(bf16x8_t*)&As[nxt][lr + p * 64][lc] = ra[p];
                *(bf16x8_t*)&Bs[nxt][lr + p * 64][lc] = rb[p];
            }
        }
        __syncthreads();
    }

    const int lr4 = (l >> 4) * 4;
    const float alpha = ch.alpha;
#pragma unroll
    for (int mi = 0; mi < 4; ++mi) {
        const long m0 = rowA + wr * 64 + mi * 16 + lr4;
#pragma unroll
        for (int ni = 0; ni < 4; ++ni) {
            const long nn = rowB + wc * 64 + ni * 16 + lm;
            const float bv = bias[nn];
#pragma unroll
            for (int r = 0; r < 4; ++r) {
                const float v = (acc[mi][ni][r] + bv) * alpha;
                const long m = m0 + r;
                if (ch.epi == 5) (ch.C2 + bz * cB)[m * ldc + nn] = f2bf(v);
                else             (ch.C  + bz * cB)[m * ldc + nn] = v;
            }
        }
    }
}

// ===========================================================================
// mgemm: R4-proven single-chunk reg-staged GEMM. EPI 4 = f32 acc+bias+resid.
// ===========================================================================
template<int BM, int EPI>
__global__ __launch_bounds__(256) void mgemm(
    const unsigned short* __restrict__ A, const unsigned short* __restrict__ Bt,
    const float* __restrict__ bias, const float* __restrict__ resid,
    float* __restrict__ C, float* __restrict__ denom,
    int K, int lda, int ldbt, int ldc)
{
    constexpr int MR = BM / 32;
    constexpr int AP = BM / 64;
    XCD_SWZ();

    __shared__ __align__(16) unsigned short As[2][BM][40];
    __shared__ __align__(16) unsigned short Bs[2][128][40];

    const int t = threadIdx.x;
    const int w = t >> 6, l = t & 63;
    const int wr = w >> 1, wc = w & 1;
    const long rowA = (long)by * BM;
    const long rowB = (long)bx * 128;

    const int lr = t >> 2;
    const int lc = (t & 3) << 3;
    const unsigned short* Ag = A  + (rowA + lr) * (long)lda  + lc;
    const unsigned short* Bg = Bt + (rowB + lr) * (long)ldbt + lc;

    const int lm = l & 15;
    const int lk = (l >> 4) * 8;

    f32x4_t acc[MR][4];
#pragma unroll
    for (int mi = 0; mi < MR; ++mi)
#pragma unroll
        for (int ni = 0; ni < 4; ++ni) acc[mi][ni] = (f32x4_t)0.0f;

    bf16x8_t ra[AP], rb[2];
#pragma unroll
    for (int p = 0; p < AP; ++p) ra[p] = *(const bf16x8_t*)(Ag + (long)p * 64 * lda);
#pragma unroll
    for (int p = 0; p < 2;  ++p) rb[p] = *(const bf16x8_t*)(Bg + (long)p * 64 * ldbt);
#pragma unroll
    for (int p = 0; p < AP; ++p) *(bf16x8_t*)&As[0][lr + p * 64][lc] = ra[p];
#pragma unroll
    for (int p = 0; p < 2;  ++p) *(bf16x8_t*)&Bs[0][lr + p * 64][lc] = rb[p];
    __syncthreads();

    const int nsteps = K >> 5;
    for (int ti = 0; ti < nsteps; ++ti) {
        const int cur = ti & 1;
        if (ti + 1 < nsteps) {
            const int kb = (ti + 1) << 5;
#pragma unroll
            for (int p = 0; p < AP; ++p) ra[p] = *(const bf16x8_t*)(Ag + (long)p * 64 * lda  + kb);
#pragma unroll
            for (int p = 0; p < 2;  ++p) rb[p] = *(const bf16x8_t*)(Bg + (long)p * 64 * ldbt + kb);
        }
        bf16x8_t af[MR], bfr[4];
#pragma unroll
        for (int mi = 0; mi < MR; ++mi)
            af[mi] = *(const bf16x8_t*)&As[cur][wr * (BM / 2) + mi * 16 + lm][lk];
#pragma unroll
        for (int ni = 0; ni < 4; ++ni)
            bfr[ni] = *(const bf16x8_t*)&Bs[cur][wc * 64 + ni * 16 + lm][lk];
#pragma unroll
        for (int mi = 0; mi < MR; ++mi)
#pragma unroll
            for (int ni = 0; ni < 4; ++ni)
                acc[mi][ni] = __builtin_amdgcn_mfma_f32_16x16x32_bf16(
                    af[mi], bfr[ni], acc[mi][ni], 0, 0, 0);
        if (ti + 1 < nsteps) {
            const int nxt = cur ^ 1;
#pragma unroll
            for (int p = 0; p < AP; ++p) *(bf16x8_t*)&As[nxt][lr + p * 64][lc] = ra[p];
#pragma unroll
            for (int p = 0; p < 2;  ++p) *(bf16x8_t*)&Bs[nxt][lr + p * 64][lc] = rb[p];
        }
        __syncthreads();
    }

    const int lr4 = (l >> 4) * 4;
#pragma unroll
    for (int mi = 0; mi < MR; ++mi) {
        const long m0 = rowA + wr * (BM / 2) + mi * 16 + lr4;
#pragma unroll
        for (int ni = 0; ni < 4; ++ni) {
            const long nn = rowB + wc * 64 + ni * 16 + lm;
            const float bv = bias[nn];
#pragma unroll
            for (int r = 0; r < 4; ++r) {
                float v = acc[mi][ni][r] + bv;
                const long m = m0 + r;
                if (EPI == 4) v += resid[m * ldc + nn];
                C[m * ldc + nn] = v;
            }
        }
    }
}

// ---------------------------------------------------------------------------
// Batched transpose + f32->bf16: src (R,C) f32 -> dst (C,R) bf16, z-indexed.
// 16B/lane stores (bf16x8). R18-proven.
// ---------------------------------------------------------------------------
struct TP4 {
    const float* s0; const float* s1; const float* s2; const float* s3;
    unsigned short* d0; unsigned short* d1; unsigned short* d2; unsigned short* d3;
};

__global__ __launch_bounds__(256) void tp_batch(TP4 tp, int R, int C)
{
    const int z = blockIdx.z;
    const float* X = (z == 0) ? tp.s0 : (z == 1) ? tp.s1 : (z == 2) ? tp.s2 : tp.s3;
    unsigned short* XT = (z == 0) ? tp.d0 : (z == 1) ? tp.d1 : (z == 2) ? tp.d2 : tp.d3;
    __shared__ float tile[64][65];
    const int t = threadIdx.x;
    const long r0 = (long)blockIdx.y * 64;
    const long c0 = (long)blockIdx.x * 64;
    const int tr = t >> 4;
    const int tc = (t & 15) << 2;
#pragma unroll
    for (int p = 0; p < 4; ++p) {
        const float4 v = *(const float4*)(X + (r0 + tr + p * 16) * C + c0 + tc);
        tile[tr + p * 16][tc + 0] = v.x;
        tile[tr + p * 16][tc + 1] = v.y;
        tile[tr + p * 16][tc + 2] = v.z;
        tile[tr + p * 16][tc + 3] = v.w;
    }
    __syncthreads();
#pragma unroll
    for (int p = 0; p < 2; ++p) {
        const int orow = (t >> 3) + p * 32;
        const int oc8  = (t & 7) * 8;
        unsigned short tmp[8];
#pragma unroll
        for (int j = 0; j < 8; ++j) tmp[j] = f2bf(tile[oc8 + j][orow]);
        *(bf16x8_t*)(XT + (c0 + orow) * (long)R + r0 + oc8) = *(const bf16x8_t*)tmp;
    }
}

// qkv weights: (NH,HS,HS) f32 x3 -> concatenated (3,NH,HS,HS) bf16 transposed
__global__ __launch_bounds__(256) void tp_qkv(
    const float* wq, const float* wk, const float* wv, unsigned short* dst)
{
    const int z = blockIdx.z;
    const int sel = z >> 3, head = z & 7;
    const float* X = ((sel == 0) ? wq : (sel == 1) ? wk : wv) + (long)head * HS * HS;
    unsigned short* XT = dst + (long)sel * NH * HS * HS + (long)head * HS * HS;
    __shared__ float tile[64][65];
    const int t = threadIdx.x;
    const long r0 = (long)blockIdx.y * 64;
    const long c0 = (long)blockIdx.x * 64;
    const int tr = t >> 4;
    const int tc = (t & 15) << 2;
#pragma unroll
    for (int p = 0; p < 4; ++p) {
        const float4 v = *(const float4*)(X + (r0 + tr + p * 16) * HS + c0 + tc);
        tile[tr + p * 16][tc + 0] = v.x;
        tile[tr + p * 16][tc + 1] = v.y;
        tile[tr + p * 16][tc + 2] = v.z;
        tile[tr + p * 16][tc + 3] = v.w;
    }
    __syncthreads();
#pragma unroll
    for (int p = 0; p < 2; ++p) {
        const int orow = (t >> 3) + p * 32;
        const int oc8  = (t & 7) * 8;
        unsigned short tmp[8];
#pragma unroll
        for (int j = 0; j < 8; ++j) tmp[j] = f2bf(tile[oc8 + j][orow]);
        *(bf16x8_t*)(XT + (c0 + orow) * (long)HS + r0 + oc8) = *(const bf16x8_t*)tmp;
    }
}

// ---------------------------------------------------------------------------
// LayerNorm over D_IN per row -> bf16
// ---------------------------------------------------------------------------
__global__ __launch_bounds__(256) void layernorm_kernel(
    const float* __restrict__ x, const float* __restrict__ w,
    const float* __restrict__ b, unsigned short* __restrict__ out)
{
    __shared__ float sh[8];
    const int row = blockIdx.x, t = threadIdx.x;
    const float* xr = x + (long)row * D_IN;
    float v[8];
    float s = 0.f, ss = 0.f;
#pragma unroll
    for (int i = 0; i < 8; ++i) {
        v[i] = xr[t + 256 * i];
        s += v[i];
        ss += v[i] * v[i];
    }
#pragma unroll
    for (int off = 32; off; off >>= 1) {
        s  += __shfl_down(s, off, 64);
        ss += __shfl_down(ss, off, 64);
    }
    const int lane = t & 63, wid = t >> 6;
    if (lane == 0) { sh[wid * 2] = s; sh[wid * 2 + 1] = ss; }
    __syncthreads();
    s = 0.f; ss = 0.f;
#pragma unroll
    for (int i = 0; i < 4; ++i) { s += sh[i * 2]; ss += sh[i * 2 + 1]; }
    const float mu  = s * (1.0f / D_IN);
    const float var = ss * (1.0f / D_IN) - mu * mu;
    const float rs  = rsqrtf(var + LN_EPS);
    unsigned short* orow = out + (long)row * D_IN;
#pragma unroll
    for (int i = 0; i < 8; ++i) {
        const int d = t + 256 * i;
        orow[d] = f2bf((v[i] - mu) * rs * w[d] + b[d]);
    }
}

// ---------------------------------------------------------------------------
// Causal conv1d (K=4, left pad 3) + SiLU.  bf16 -> bf16
// ---------------------------------------------------------------------------
__global__ void conv_silu_kernel(const unsigned short* __restrict__ xl,
                                 const float* __restrict__ cw,
                                 const float* __restrict__ cb,
                                 unsigned short* __restrict__ out)
{
    const long idx = (long)blockIdx.x * blockDim.x + threadIdx.x;
    if (idx >= (long)B_ROWS * D_UP) return;
    const int d = (int)(idx & (D_UP - 1));
    const float w0 = cw[0], w1 = cw[1], w2 = cw[2], w3 = cw[3];
    float acc = cb[0] + w3 * bf2f(xl[idx]);
    if (d >= 1) acc += w2 * bf2f(xl[idx - 1]);
    if (d >= 2) acc += w1 * bf2f(xl[idx - 2]);
    if (d >= 3) acc += w0 * bf2f(xl[idx - 3]);
    out[idx] = f2bf(siluf_(acc));
}

// ---------------------------------------------------------------------------
// Stabilized exponential gating, float4-vectorized -> m_t, c_t, n_t
// ---------------------------------------------------------------------------
__global__ void gating_kernel(const float4* __restrict__ it, const float4* __restrict__ ft,
                              const float4* __restrict__ mp, const float4* __restrict__ cp,
                              const float4* __restrict__ np_, const float4* __restrict__ kk,
                              const float4* __restrict__ vv,
                              float4* __restrict__ mt, float4* __restrict__ ct,
                              float4* __restrict__ nt)
{
    const long idx = (long)blockIdx.x * blockDim.x + threadIdx.x;
    if (idx >= (long)B_ROWS * D_HID / 4) return;
    const float4 i4 = it[idx], f4 = ft[idx], mp4 = mp[idx];
    const float4 cp4 = cp[idx], np4 = np_[idx], k4 = kk[idx], v4 = vv[idx];
    float4 m4, c4, n4;
#pragma unroll
    for (int j = 0; j < 4; ++j) {
        const float i_t = (&i4.x)[j];
        const float f_t = (&f4.x)[j] + (&mp4.x)[j];
        const float m_t = fmaxf(f_t, i_t);
        const float i_g = expf(i_t - m_t);
        const float f_g = expf(f_t - m_t);
        const float kv  = (&k4.x)[j];
        (&c4.x)[j] = f_g * (&cp4.x)[j] + i_g * ((&v4.x)[j] * kv);
        (&n4.x)[j] = f_g * (&np4.x)[j] + i_g * kv;
        (&m4.x)[j] = m_t;
    }
    ct[idx] = c4;
    nt[idx] = n4;
    mt[idx] = m4;
}

// ---------------------------------------------------------------------------
// Fused: h_t = sigmoid(op)*c_t*q/denom  +  GroupNorm + skip + silu-gate
// ---------------------------------------------------------------------------
__global__ __launch_bounds__(128) void hgnorm_kernel(
    const unsigned short* __restrict__ op, const float* __restrict__ ct,
    const float* __restrict__ qb, const float* __restrict__ denom,
    const float* __restrict__ gw, const float* __restrict__ gb,
    const unsigned short* __restrict__ xskip, const unsigned short* __restrict__ xupR,
    float* __restrict__ ht, unsigned short* __restrict__ out)
{
    __shared__ float sh[4];
    const int b = blockIdx.x >> 3, h = blockIdx.x & 7;
    const int t = threadIdx.x;
    const long base = (long)b * D_HID + h * HS;
    float v[4];
    float s = 0.f, ss = 0.f;
#pragma unroll
    for (int i = 0; i < 4; ++i) {
        const long ix = base + t + 128 * i;
        const int  dg = h * HS + t + 128 * i;
        const float hv = sigmoidf_(bf2f(op[ix])) * ct[ix] * qb[ix] / denom[dg];
        ht[ix] = hv;
        v[i] = hv;
        s += hv;
        ss += hv * hv;
    }
#pragma unroll
    for (int off = 32; off; off >>= 1) {
        s  += __shfl_down(s, off, 64);
        ss += __shfl_down(ss, off, 64);
    }
    if ((t & 63) == 0) { sh[(t >> 6) * 2] = s; sh[(t >> 6) * 2 + 1] = ss; }
    __syncthreads();
    s = sh[0] + sh[2];
    ss = sh[1] + sh[3];
    const float mu  = s * (1.0f / HS);
    const float var = ss * (1.0f / HS) - mu * mu;
    const float rs  = rsqrtf(var + LN_EPS);
#pragma unroll
    for (int i = 0; i < 4; ++i) {
        const int  dg = h * HS + t + 128 * i;
        const long ix = base + t + 128 * i;
        const float g = (v[i] - mu) * rs * gw[dg] + gb[dg];
        out[ix] = f2bf((g + bf2f(xskip[ix])) * siluf_(bf2f(xupR[ix])));
    }
}

// ---------------------------------------------------------------------------
extern "C" void kernel_launch(void* const* d_in, const int* in_sizes, int n_in,
                              void* d_out, int out_size, void* d_ws, size_t ws_size,
                              hipStream_t stream)
{
    const float* x      = (const float*)d_in[0];
    const float* c_prev = (const float*)d_in[2];
    const float* n_prev = (const float*)d_in[3];
    const float* m_prev = (const float*)d_in[4];
    const float* ln_w   = (const float*)d_in[5];
    const float* ln_b   = (const float*)d_in[6];
    const float* upL_w  = (const float*)d_in[7];
    const float* upL_b  = (const float*)d_in[8];
    const float* upR_w  = (const float*)d_in[9];
    const float* upR_b  = (const float*)d_in[10];
    const float* conv_w = (const float*)d_in[11];
    const float* conv_b = (const float*)d_in[12];
    const float* skip_w = (const float*)d_in[13];
    const float* skip_b = (const float*)d_in[14];
    const float* wq     = (const float*)d_in[15];
    const float* bq     = (const float*)d_in[16];
    const float* wk     = (const float*)d_in[17];
    const float* bk     = (const float*)d_in[18];
    const float* wv     = (const float*)d_in[19];
    const float* bv     = (const float*)d_in[20];
    const float* wi_w   = (const float*)d_in[21];
    const float* wi_b   = (const float*)d_in[22];
    const float* wf_w   = (const float*)d_in[23];
    const float* wf_b   = (const float*)d_in[24];
    const float* wo_w   = (const float*)d_in[25];
    const float* wo_b   = (const float*)d_in[26];
    const float* gn_w   = (const float*)d_in[27];
    const float* gn_b   = (const float*)d_in[28];
    const float* down_w = (const float*)d_in[29];
    const float* down_b = (const float*)d_in[30];

    float* out     = (float*)d_out;
    float* final_o = out;                       // (1024, 2048)  [0, 2M) f32
    float* ht      = final_o + 2097152;         // [2M, 6M)
    float* ct      = ht + 4194304;              // [6M, 10M)
    float* nt      = ct + 4194304;              // [10M, 14M)
    float* mt      = nt + 4194304;              // [14M, 18M)

    // d_out scratch: WTA = ht+ct, WTB = nt+mt; consumed before gating/hgnorm
    // write those regions (stream-serial).
    unsigned short* WTA = (unsigned short*)ht;
    unsigned short* WTB = (unsigned short*)nt;

    // ---- workspace layout (float units; M = 1M floats). Peak ≈ 162MB.
    const long M = 1048576;
    float* ws = (float*)d_ws;
    float* qb  = ws +  0 * M;                                  // [0,4M)   step7..11
    float* kb  = ws +  4 * M;                                  // [4,8M)   step7..8
    float* vb  = ws +  8 * M;                                  // [8,12M)  step7..8
    float* itb = ws + 12 * M;                                  // [12,16M) step6..8
    float* ftb = ws + 16 * M;                                  // [16,20M) step6..8
    unsigned short* xupR_bf  = (unsigned short*)(ws + 20 * M); // step3..11
    unsigned short* xskip_bf = (unsigned short*)(ws + 22 * M); // step6..11
    unsigned short* opb_bf   = (unsigned short*)(ws + 24 * M); // step6..11
    unsigned short* xnorm_bf = (unsigned short*)(ws + 26 * M); // step1..3
    unsigned short* xupL_bf  = (unsigned short*)(ws + 27 * M); // step3..7
    unsigned short* xconv_bf = (unsigned short*)(ws + 29 * M); // step4..7
    float* denom             = ws + 31 * M;                    // 4096 f32
    unsigned short* WTC      = (unsigned short*)(ws + 32 * M); // wf^T, step5..6
    unsigned short* WTD      = (unsigned short*)(ws +  0 * M); // wo^T, step5..6 (dead before qb/kb)
    unsigned short* ntT      = (unsigned short*)(ws + 26 * M); // step9 (xnorm/xupL dead)
    unsigned short* qT       = (unsigned short*)(ws + 28 * M); // step9 (xupL/xconv dead)
    unsigned short* dwT      = (unsigned short*)(ws + 12 * M); // down^T, step10..12
    unsigned short* tmp_bf   = (unsigned short*)(ws +  8 * M); // step11..12 (vb dead)

    const float kscale = 1.0f / sqrtf((float)HS);
    const long HS2 = (long)HS * HS;
    MGChunk cz = {};
    MCChunk mz = {};

    // 1. LayerNorm -> bf16
    layernorm_kernel<<<B_ROWS, 256, 0, stream>>>(x, ln_w, ln_b, xnorm_bf);

    // 2. upL^T, upR^T -> WTA
    {
        TP4 tp = { upL_w, upR_w, nullptr, nullptr, WTA, WTA + 8388608, nullptr, nullptr };
        tp_batch<<<dim3(64, 32, 2), 256, 0, stream>>>(tp, D_IN, D_UP);
    }
    // 3. upL | upR GEMM (R4-proven mgemm_mc, grid 512)
    {
        MCChunk a = { xnorm_bf, WTA,           upL_b, nullptr, xupL_bf, 1.0f, 5 };
        MCChunk b = { xnorm_bf, WTA + 8388608, upR_b, nullptr, xupR_bf, 1.0f, 5 };
        mgemm_mc<2><<<dim3(64, 8, 1), 256, 0, stream>>>(
            a, b, mz, D_IN, D_IN, D_IN, D_HID, 32, 0, 0, 0, 0);
    }

    // 4. causal conv + silu -> bf16
    conv_silu_kernel<<<(B_ROWS * D_UP) / 256, 256, 0, stream>>>(xupL_bf, conv_w, conv_b, xconv_bf);

    // 5. skip^T->WTA, wi^T->WTB, wf^T->WTC, wo^T->WTD
    {
        TP4 tp = { skip_w, wi_w, wf_w, wo_w, WTA, WTB, WTC, WTD };
        tp_batch<<<dim3(64, 64, 4), 256, 0, stream>>>(tp, D_UP, D_HID);
    }
    // 6. skip | wi | wf | wo in ONE mg256 dispatch (grid 512)
    {
        MGChunk a = { xconv_bf, WTA, skip_b, nullptr, nullptr, xskip_bf, nullptr, 1.0f, 5 };
        MGChunk b = { xconv_bf, WTB, wi_b,   nullptr, itb,     nullptr,  nullptr, 1.0f, 0 };
        MGChunk c = { xconv_bf, WTC, wf_b,   nullptr, ftb,     nullptr,  nullptr, 1.0f, 0 };
        MGChunk d = { xupL_bf,  WTD, wo_b,   nullptr, nullptr, opb_bf,   nullptr, 1.0f, 5 };
        mg256<4><<<dim3(128, 4, 1), 256, 0, stream>>>(
            a, b, c, d, D_UP, D_UP, D_UP, D_HID, 32, 0, 0, 0, 0);
    }

    // 7. qkv^T -> WTA, then q | k | v head-batched (R4-proven mgemm_mc, grid 768)
    tp_qkv<<<dim3(8, 8, 24), 256, 0, stream>>>(wq, wk, wv, WTA);
    {
        MCChunk a = { xconv_bf, WTA,                bq, qb, nullptr, 1.0f,   0 };
        MCChunk b = { xconv_bf, WTA + NH * HS2,     bk, kb, nullptr, kscale, 0 };
        MCChunk c = { xupL_bf,  WTA + 2 * NH * HS2, bv, vb, nullptr, 1.0f,   0 };
        mgemm_mc<3><<<dim3(12, 8, NH), 256, 0, stream>>>(
            a, b, c, HS, D_UP, HS, D_HID, 4, HS, HS2, HS, HS);
    }

    // 8. gating (float4) -> m_t, c_t, n_t
    gating_kernel<<<(B_ROWS * D_HID / 4) / 256, 256, 0, stream>>>(
        (const float4*)itb, (const float4*)ftb, (const float4*)m_prev,
        (const float4*)c_prev, (const float4*)n_prev, (const float4*)kb,
        (const float4*)vb, (float4*)mt, (float4*)ct, (float4*)nt);

    // 9. nt^T, q^T -> ntT/qT; denom = rowwise max |n_t^T q| via mg256 epi3
    {
        TP4 tp = { nt, qb, nullptr, nullptr, ntT, qT, nullptr, nullptr };
        tp_batch<<<dim3(64, 16, 2), 256, 0, stream>>>(tp, B_ROWS, D_HID);
    }
    hipMemsetAsync(denom, 0, D_HID * sizeof(float), stream);
    {
        MGChunk a = { ntT, qT, nullptr, nullptr, nullptr, nullptr, denom, 1.0f, 3 };
        mg256<1><<<dim3(32, 16, 1), 256, 0, stream>>>(
            a, cz, cz, cz, B_ROWS, B_ROWS, B_ROWS, 0, 32, 0, 0, 0, 0);
    }

    // 10. down^T -> dwT
    {
        TP4 tp = { down_w, nullptr, nullptr, nullptr, dwT, nullptr, nullptr, nullptr };
        tp_batch<<<dim3(32, 64, 1), 256, 0, stream>>>(tp, D_HID, D_IN);
    }

    // 11. fused h_t + GroupNorm + skip + silu-gate -> tmp_bf (and ht to d_out)
    hgnorm_kernel<<<B_ROWS * NH, 128, 0, stream>>>(
        opb_bf, ct, qb, denom, gn_w, gn_b, xskip_bf, xupR_bf, ht, tmp_bf);

    // 12. down-projection + residual -> final (R4-proven mgemm<64,4>, grid 256)
    mgemm<64, 4><<<dim3(16, 16, 1), 256, 0, stream>>>(
        tmp_bf, dwT, down_b, x, final_o, nullptr, D_HID, D_HID, D_HID, D_IN);
}